// Round 9
// baseline (171.002 us; speedup 1.0000x reference)
//
#include <hip/hip_runtime.h>
#include <hip/hip_bf16.h>

namespace {

typedef __attribute__((ext_vector_type(8))) short bf16x8;
typedef __attribute__((ext_vector_type(4))) float f32x4;

union BF8U { unsigned u[4]; bf16x8 v; };

__device__ __forceinline__ unsigned pk2(float a, float b) {
    union { __hip_bfloat162 h2; unsigned u; } c;
    c.h2 = __float22bfloat162_rn(float2{a, b});
    return c.u;
}
__device__ __forceinline__ unsigned short b1(float f) {
    union { __hip_bfloat16 h; unsigned short s; } c;
    c.h = __float2bfloat16(f);
    return c.s;
}
__device__ __forceinline__ int SWZ(int byteoff, int row) {
    return byteoff ^ ((row & 7) << 4);
}

// LDS: two 16 KB tiles, rows = 64 x 256B (128 bf16), XOR-swizzled.
constexpr int SX  = 0;        // LN out; (fallback path reuses as MO-out)
constexpr int SAO = 16384;    // attention out [i][d]
constexpr int LDS_BYTES = 32768;

// Workspace layout (USEWS):
//   shorts [0, 49152)      : bf16 Wqkv' = wqkv * diag(ln_gamma)   [384][128]
//   shorts [49152, 65536)  : bf16 Wcomb = wout @ wmo              [128][128]
//   floats fb[0, 384)      : bqkv' = bqkv + wqkv @ ln_beta
//   floats fb[384, 512)    : bcomb = bout + wout @ bmo
// fb = (float*)(wsb + 65536); total bytes = 131072 + 2048 = 133120.

template<bool USEWS>
__device__ __forceinline__ bf16x8 load_wfrag(const unsigned short* wsb, const float* wf, int idx) {
    if constexpr (USEWS) {
        return *(const bf16x8*)(wsb + idx);
    } else {
        const float4 f0 = *(const float4*)(wf + idx);
        const float4 f1 = *(const float4*)(wf + idx + 4);
        bf16x8 r;
        r[0] = (short)b1(f0.x); r[1] = (short)b1(f0.y);
        r[2] = (short)b1(f0.z); r[3] = (short)b1(f0.w);
        r[4] = (short)b1(f1.x); r[5] = (short)b1(f1.y);
        r[6] = (short)b1(f1.z); r[7] = (short)b1(f1.w);
        return r;
    }
}

__global__ void conv_w2(const float* __restrict__ wqkv, const float* __restrict__ bqkv,
                        const float* __restrict__ wmo,  const float* __restrict__ bmo,
                        const float* __restrict__ wout, const float* __restrict__ bout,
                        const float* __restrict__ lng,  const float* __restrict__ lnb,
                        unsigned short* __restrict__ dst) {
    float* fb = (float*)(dst + 65536);
    const int bid = blockIdx.x, t = threadIdx.x;
    if (bid < 192) {
        const int idx = bid * 256 + t;
        dst[idx] = b1(wqkv[idx] * lng[idx & 127]);
    } else if (bid < 256) {
        const int e = (bid - 192) * 256 + t;
        const int o = e >> 7, i = e & 127;
        const float* wo = wout + o * 128;
        float s = 0.f;
        for (int k = 0; k < 128; ++k) s += wo[k] * wmo[k * 128 + i];
        dst[49152 + e] = b1(s);
    } else if (bid < 258) {
        const int o = (bid - 256) * 256 + t;
        if (o < 384) {
            const float* wr = wqkv + o * 128;
            float s = 0.f;
            for (int i = 0; i < 128; ++i) s += wr[i] * lnb[i];
            fb[o] = bqkv[o] + s;
        }
    } else {
        if (t < 128) {
            const float* wo = wout + t * 128;
            float s = 0.f;
            for (int k = 0; k < 128; ++k) s += wo[k] * bmo[k];
            fb[384 + t] = bout[t] + s;
        }
    }
}

template<bool USEWS>
__global__ __launch_bounds__(256, 4)
void swin_mfma(const float* __restrict__ x,
               const float* __restrict__ lng, const float* __restrict__ lnb,
               const float* __restrict__ wqkv, const float* __restrict__ bqkv,
               const float* __restrict__ wmo,  const float* __restrict__ bmo,
               const float* __restrict__ wout, const float* __restrict__ bout,
               const unsigned short* __restrict__ wsb,
               float* __restrict__ out)
{
    __shared__ char lds[LDS_BYTES];

    const float* fb = USEWS ? (const float*)(wsb + 65536) : nullptr;

    const int wid  = blockIdx.x;
    const int b    = wid >> 8;
    const int wh   = (wid >> 4) & 15;
    const int ww   = wid & 15;
    const int t    = threadIdx.x;
    const int lane = t & 63;
    const int h    = t >> 6;          // wave == head
    const int lr   = lane & 15;
    const int g    = lane >> 4;       // 0..3
    const int hb   = h * 32;

    const size_t base = ((size_t)(b * 112 + wh * 7) * 112 + ww * 7) * 128;

    // ================= LayerNorm (4 lanes per token) =================
    if (t < 240) *(f32x4*)(lds + SX + 49 * 256 + t * 16) = f32x4{0.f, 0.f, 0.f, 0.f};
    {
        const int tok = t >> 2, q4 = t & 3;
        if (tok < 49) {
            const float* xr = x + base + (size_t)((tok / 7) * 112 + (tok % 7)) * 128;
            float4 xv[8];
            float s1 = 0.f, s2 = 0.f;
            #pragma unroll
            for (int j = 0; j < 8; ++j) {
                xv[j] = *(const float4*)(xr + j * 16 + q4 * 4);
                s1 += xv[j].x + xv[j].y + xv[j].z + xv[j].w;
                s2 += xv[j].x * xv[j].x + xv[j].y * xv[j].y
                    + xv[j].z * xv[j].z + xv[j].w * xv[j].w;
            }
            s1 += __shfl_xor(s1, 1); s1 += __shfl_xor(s1, 2);
            s2 += __shfl_xor(s2, 1); s2 += __shfl_xor(s2, 2);
            const float mu  = s1 * (1.f / 128.f);
            const float inv = rsqrtf(s2 * (1.f / 128.f) - mu * mu + 1e-5f);
            #pragma unroll
            for (int j = 0; j < 8; ++j) {
                float y0, y1, y2, y3;
                if constexpr (USEWS) {
                    y0 = (xv[j].x - mu) * inv;
                    y1 = (xv[j].y - mu) * inv;
                    y2 = (xv[j].z - mu) * inv;
                    y3 = (xv[j].w - mu) * inv;
                } else {
                    const float4 gm = *(const float4*)(lng + j * 16 + q4 * 4);
                    const float4 bt = *(const float4*)(lnb + j * 16 + q4 * 4);
                    y0 = (xv[j].x - mu) * inv * gm.x + bt.x;
                    y1 = (xv[j].y - mu) * inv * gm.y + bt.y;
                    y2 = (xv[j].z - mu) * inv * gm.z + bt.z;
                    y3 = (xv[j].w - mu) * inv * gm.w + bt.w;
                }
                uint2 w; w.x = pk2(y0, y1); w.y = pk2(y2, y3);
                *(uint2*)(lds + SX + tok * 256 + SWZ(j * 32 + q4 * 8, tok)) = w;
            }
        }
    }
    __syncthreads();   // barrier #1

    // ---- in-wave redistribution: C-frag (idx on g*4+r, tiles) -> A/B-frag (idx on g*8+d) ----
    const int s01  = lr + ((lane & 16) ? 32 : 0);   // src lane for words 0,1
    const int s23  = s01 + 16;                      // src lane for words 2,3
    const bool hiT = (lane & 32) != 0;              // tile-parity select
    auto RD4 = [&](unsigned e0, unsigned e1, unsigned o0, unsigned o1) -> bf16x8 {
        BF8U r;
        const unsigned v0 = hiT ? o0 : e0;
        const unsigned v1 = hiT ? o1 : e1;
        r.u[0] = (unsigned)__shfl((int)v0, s01);
        r.u[1] = (unsigned)__shfl((int)v1, s01);
        r.u[2] = (unsigned)__shfl((int)v0, s23);
        r.u[3] = (unsigned)__shfl((int)v1, s23);
        return r.v;
    };

    // ============ Q pass: projection SWAPPED (D[o][token]) -> qb frags ============
    bf16x8 qb[4];   // B-frag per i-tile: col-lane=i, k=o(d)
    {
        f32x4 aQ[2][4];
        #pragma unroll
        for (int ot = 0; ot < 2; ++ot)
            #pragma unroll
            for (int tt = 0; tt < 4; ++tt) aQ[ot][tt] = f32x4{0.f, 0.f, 0.f, 0.f};
        #pragma unroll
        for (int kk = 0; kk < 4; ++kk) {
            bf16x8 xa[4];
            #pragma unroll
            for (int tt = 0; tt < 4; ++tt) {
                int row = tt * 16 + lr;
                xa[tt] = *(bf16x8*)(lds + SX + row * 256 + SWZ(kk * 64 + g * 16, row));
            }
            #pragma unroll
            for (int ot = 0; ot < 2; ++ot) {
                bf16x8 wq = load_wfrag<USEWS>(wsb, wqkv, (hb + ot * 16 + lr) * 128 + kk * 32 + g * 8);
                #pragma unroll
                for (int tt = 0; tt < 4; ++tt)
                    aQ[ot][tt] = __builtin_amdgcn_mfma_f32_16x16x32_bf16(wq, xa[tt], aQ[ot][tt], 0, 0, 0);
            }
        }
        unsigned pkQ[4][2][2];
        #pragma unroll
        for (int ot = 0; ot < 2; ++ot) {
            float4 bq;
            if constexpr (USEWS) bq = *(const float4*)(fb + hb + ot * 16 + g * 4);
            else                 bq = *(const float4*)(bqkv + hb + ot * 16 + g * 4);
            #pragma unroll
            for (int nti = 0; nti < 4; ++nti) {
                const float q0 = (aQ[ot][nti][0] + bq.x) * 0.17677669529663687f;
                const float q1 = (aQ[ot][nti][1] + bq.y) * 0.17677669529663687f;
                const float q2 = (aQ[ot][nti][2] + bq.z) * 0.17677669529663687f;
                const float q3 = (aQ[ot][nti][3] + bq.w) * 0.17677669529663687f;
                pkQ[nti][ot][0] = pk2(q0, q1); pkQ[nti][ot][1] = pk2(q2, q3);
            }
        }
        #pragma unroll
        for (int nti = 0; nti < 4; ++nti)
            qb[nti] = RD4(pkQ[nti][0][0], pkQ[nti][0][1], pkQ[nti][1][0], pkQ[nti][1][1]);
    }

    // ============ K pass: projection SWAPPED (D[o][token]) -> kb frags ============
    bf16x8 kb[4];   // A-frag per j-tile: row-lane=j, k=o(d)
    {
        f32x4 aK[2][4];
        #pragma unroll
        for (int ot = 0; ot < 2; ++ot)
            #pragma unroll
            for (int tt = 0; tt < 4; ++tt) aK[ot][tt] = f32x4{0.f, 0.f, 0.f, 0.f};
        #pragma unroll
        for (int kk = 0; kk < 4; ++kk) {
            bf16x8 xa[4];
            #pragma unroll
            for (int tt = 0; tt < 4; ++tt) {
                int row = tt * 16 + lr;
                xa[tt] = *(bf16x8*)(lds + SX + row * 256 + SWZ(kk * 64 + g * 16, row));
            }
            #pragma unroll
            for (int ot = 0; ot < 2; ++ot) {
                bf16x8 wk = load_wfrag<USEWS>(wsb, wqkv, (128 + hb + ot * 16 + lr) * 128 + kk * 32 + g * 8);
                #pragma unroll
                for (int tt = 0; tt < 4; ++tt)
                    aK[ot][tt] = __builtin_amdgcn_mfma_f32_16x16x32_bf16(wk, xa[tt], aK[ot][tt], 0, 0, 0);
            }
        }
        unsigned pkK[4][2][2];
        #pragma unroll
        for (int ot = 0; ot < 2; ++ot) {
            float4 bk;
            if constexpr (USEWS) bk = *(const float4*)(fb + 128 + hb + ot * 16 + g * 4);
            else                 bk = *(const float4*)(bqkv + 128 + hb + ot * 16 + g * 4);
            #pragma unroll
            for (int nti = 0; nti < 4; ++nti) {
                pkK[nti][ot][0] = pk2(aK[ot][nti][0] + bk.x, aK[ot][nti][1] + bk.y);
                pkK[nti][ot][1] = pk2(aK[ot][nti][2] + bk.z, aK[ot][nti][3] + bk.w);
            }
        }
        #pragma unroll
        for (int mtj = 0; mtj < 4; ++mtj)
            kb[mtj] = RD4(pkK[mtj][0][0], pkK[mtj][0][1], pkK[mtj][1][0], pkK[mtj][1][1]);
    }

    // ============ scores S[j][i] = mfma(K, Q) + softmax, i-tiles in 2 halves ============
    unsigned pkP[4][4][2];   // [i-tile][j-tile][pair]
    #pragma unroll
    for (int half = 0; half < 2; ++half) {
        f32x4 S[4][2];   // [j-tile][i-within-half]
        #pragma unroll
        for (int mtj = 0; mtj < 4; ++mtj)
            #pragma unroll
            for (int ni = 0; ni < 2; ++ni)
                S[mtj][ni] = __builtin_amdgcn_mfma_f32_16x16x32_bf16(kb[mtj], qb[half * 2 + ni],
                                                                     f32x4{0.f, 0.f, 0.f, 0.f}, 0, 0, 0);
        // mask keys j >= 49 (j = 48 + g*4 + r in tile 3)
        #pragma unroll
        for (int ni = 0; ni < 2; ++ni)
            #pragma unroll
            for (int r = 0; r < 4; ++r)
                if (r != 0 || g != 0) S[3][ni][r] = -1e30f;

        #pragma unroll
        for (int ni = 0; ni < 2; ++ni) {
            const int nti = half * 2 + ni;
            // tree max
            float v[16];
            #pragma unroll
            for (int mtj = 0; mtj < 4; ++mtj)
                #pragma unroll
                for (int r = 0; r < 4; ++r) v[mtj * 4 + r] = S[mtj][ni][r];
            #pragma unroll
            for (int st = 8; st >= 1; st >>= 1)
                #pragma unroll
                for (int q = 0; q < st; ++q) v[q] = fmaxf(v[q], v[q + st]);
            float m = v[0];
            m = fmaxf(m, __shfl_xor(m, 16));
            m = fmaxf(m, __shfl_xor(m, 32));
            // exp + tree sum
            float p[16];
            #pragma unroll
            for (int mtj = 0; mtj < 4; ++mtj)
                #pragma unroll
                for (int r = 0; r < 4; ++r) p[mtj * 4 + r] = __expf(S[mtj][ni][r] - m);
            float s8[8];
            #pragma unroll
            for (int q = 0; q < 8; ++q) s8[q] = p[q] + p[q + 8];
            #pragma unroll
            for (int st = 4; st >= 1; st >>= 1)
                #pragma unroll
                for (int q = 0; q < st; ++q) s8[q] += s8[q + st];
            float sum = s8[0];
            sum += __shfl_xor(sum, 16);
            sum += __shfl_xor(sum, 32);
            const float rinv = 1.0f / sum;
            #pragma unroll
            for (int mtj = 0; mtj < 4; ++mtj) {
                pkP[nti][mtj][0] = pk2(p[mtj * 4 + 0] * rinv, p[mtj * 4 + 1] * rinv);
                pkP[nti][mtj][1] = pk2(p[mtj * 4 + 2] * rinv, p[mtj * 4 + 3] * rinv);
            }
        }
    }

    // ============ V pass: projection NORMAL (D[token][o]) ============
    unsigned pkV[2][4][2];   // [d-tile][token-tile][pair]
    {
        f32x4 aV[4][2];
        #pragma unroll
        for (int mt = 0; mt < 4; ++mt) {
            aV[mt][0] = f32x4{0.f, 0.f, 0.f, 0.f};
            aV[mt][1] = f32x4{0.f, 0.f, 0.f, 0.f};
        }
        #pragma unroll
        for (int kk = 0; kk < 4; ++kk) {
            bf16x8 xa[4];
            #pragma unroll
            for (int tt = 0; tt < 4; ++tt) {
                int row = tt * 16 + lr;
                xa[tt] = *(bf16x8*)(lds + SX + row * 256 + SWZ(kk * 64 + g * 16, row));
            }
            bf16x8 wv0 = load_wfrag<USEWS>(wsb, wqkv, (256 + hb + lr) * 128 + kk * 32 + g * 8);
            bf16x8 wv1 = load_wfrag<USEWS>(wsb, wqkv, (256 + hb + 16 + lr) * 128 + kk * 32 + g * 8);
            #pragma unroll
            for (int mt = 0; mt < 4; ++mt) {
                aV[mt][0] = __builtin_amdgcn_mfma_f32_16x16x32_bf16(xa[mt], wv0, aV[mt][0], 0, 0, 0);
                aV[mt][1] = __builtin_amdgcn_mfma_f32_16x16x32_bf16(xa[mt], wv1, aV[mt][1], 0, 0, 0);
            }
        }
        const float bv0 = USEWS ? fb[256 + hb + lr]      : bqkv[256 + hb + lr];
        const float bv1 = USEWS ? fb[256 + hb + 16 + lr] : bqkv[256 + hb + 16 + lr];
        #pragma unroll
        for (int mt = 0; mt < 4; ++mt) {
            pkV[0][mt][0] = pk2(aV[mt][0][0] + bv0, aV[mt][0][1] + bv0);
            pkV[0][mt][1] = pk2(aV[mt][0][2] + bv0, aV[mt][0][3] + bv0);
            pkV[1][mt][0] = pk2(aV[mt][1][0] + bv1, aV[mt][1][1] + bv1);
            pkV[1][mt][1] = pk2(aV[mt][1][2] + bv1, aV[mt][1][3] + bv1);
        }
    }

    // ============ PV (swapped): O[d][i] = mfma(V, P) -> coalesced uint2 O-writes ============
    {
        bf16x8 vb[2][2];   // [kk][d-tile]; as A-frag: row-lane=d, k=j
        #pragma unroll
        for (int kk = 0; kk < 2; ++kk)
            #pragma unroll
            for (int ntd = 0; ntd < 2; ++ntd)
                vb[kk][ntd] = RD4(pkV[ntd][2 * kk][0], pkV[ntd][2 * kk][1],
                                  pkV[ntd][2 * kk + 1][0], pkV[ntd][2 * kk + 1][1]);
        f32x4 O[2][4];   // [d-tile][i-tile]: col-lane=i, reg rows = d
        #pragma unroll
        for (int mtd = 0; mtd < 2; ++mtd)
            #pragma unroll
            for (int nti = 0; nti < 4; ++nti) O[mtd][nti] = f32x4{0.f, 0.f, 0.f, 0.f};
        #pragma unroll
        for (int nti = 0; nti < 4; ++nti) {
            bf16x8 pa0 = RD4(pkP[nti][0][0], pkP[nti][0][1], pkP[nti][1][0], pkP[nti][1][1]);
            bf16x8 pa1 = RD4(pkP[nti][2][0], pkP[nti][2][1], pkP[nti][3][0], pkP[nti][3][1]);
            #pragma unroll
            for (int mtd = 0; mtd < 2; ++mtd) {
                O[mtd][nti] = __builtin_amdgcn_mfma_f32_16x16x32_bf16(vb[0][mtd], pa0, O[mtd][nti], 0, 0, 0);
                O[mtd][nti] = __builtin_amdgcn_mfma_f32_16x16x32_bf16(vb[1][mtd], pa1, O[mtd][nti], 0, 0, 0);
            }
        }
        #pragma unroll
        for (int mtd = 0; mtd < 2; ++mtd)
            #pragma unroll
            for (int nti = 0; nti < 4; ++nti) {
                const int i = nti * 16 + lr;
                const int dbyte = (hb + mtd * 16 + g * 4) * 2;   // 8B-aligned
                uint2 w;
                w.x = pk2(O[mtd][nti][0], O[mtd][nti][1]);
                w.y = pk2(O[mtd][nti][2], O[mtd][nti][3]);
                *(uint2*)(lds + SAO + i * 256 + SWZ(dbyte, i)) = w;
            }
    }
    __syncthreads();   // barrier #2

    if constexpr (USEWS) {
        // ============ fused (MO∘OUT) projection + residual, kk-outer ============
        f32x4 acc[4][2];
        #pragma unroll
        for (int mt = 0; mt < 4; ++mt) {
            acc[mt][0] = f32x4{0.f, 0.f, 0.f, 0.f};
            acc[mt][1] = f32x4{0.f, 0.f, 0.f, 0.f};
        }
        #pragma unroll
        for (int kk = 0; kk < 4; ++kk) {
            bf16x8 a4[4];
            #pragma unroll
            for (int mt = 0; mt < 4; ++mt) {
                int row = mt * 16 + lr;
                a4[mt] = *(bf16x8*)(lds + SAO + row * 256 + SWZ(g * 16 + kk * 64, row));
            }
            bf16x8 b0 = *(const bf16x8*)(wsb + 49152 + (hb + lr) * 128 + kk * 32 + g * 8);
            bf16x8 b1f = *(const bf16x8*)(wsb + 49152 + (hb + 16 + lr) * 128 + kk * 32 + g * 8);
            #pragma unroll
            for (int mt = 0; mt < 4; ++mt) {
                acc[mt][0] = __builtin_amdgcn_mfma_f32_16x16x32_bf16(a4[mt], b0,  acc[mt][0], 0, 0, 0);
                acc[mt][1] = __builtin_amdgcn_mfma_f32_16x16x32_bf16(a4[mt], b1f, acc[mt][1], 0, 0, 0);
            }
        }
        #pragma unroll
        for (int ntl = 0; ntl < 2; ++ntl) {
            const int oc = hb + ntl * 16 + lr;
            const float bias = fb[384 + oc];
            #pragma unroll
            for (int mt = 0; mt < 4; ++mt)
                #pragma unroll
                for (int r = 0; r < 4; ++r) {
                    const int row = mt * 16 + g * 4 + r;
                    if (row < 49) {
                        const size_t gi = base + (size_t)((row / 7) * 112 + (row % 7)) * 128 + oc;
                        out[gi] = x[gi] + acc[mt][ntl][r] + bias;
                    }
                }
        }
    } else {
        // ============ fallback: MO projection -> SX, barrier, OUT + residual ============
        {
            bf16x8 a[4][4];
            #pragma unroll
            for (int mt = 0; mt < 4; ++mt)
                #pragma unroll
                for (int kk = 0; kk < 4; ++kk) {
                    int row = mt * 16 + lr;
                    a[mt][kk] = *(bf16x8*)(lds + SAO + row * 256 + SWZ(g * 16 + kk * 64, row));
                }
            #pragma unroll
            for (int ntl = 0; ntl < 2; ++ntl) {
                const int oc = hb + ntl * 16 + lr;
                bf16x8 bfr[4];
                #pragma unroll
                for (int kk = 0; kk < 4; ++kk)
                    bfr[kk] = load_wfrag<false>(nullptr, wmo, oc * 128 + kk * 32 + g * 8);
                f32x4 acc[4];
                #pragma unroll
                for (int mt = 0; mt < 4; ++mt) acc[mt] = f32x4{0.f, 0.f, 0.f, 0.f};
                #pragma unroll
                for (int kk = 0; kk < 4; ++kk)
                    #pragma unroll
                    for (int mt = 0; mt < 4; ++mt)
                        acc[mt] = __builtin_amdgcn_mfma_f32_16x16x32_bf16(a[mt][kk], bfr[kk], acc[mt], 0, 0, 0);
                const float bias = bmo[oc];
                #pragma unroll
                for (int mt = 0; mt < 4; ++mt)
                    #pragma unroll
                    for (int r = 0; r < 4; ++r) {
                        int row = mt * 16 + g * 4 + r;
                        *(unsigned short*)(lds + SX + row * 256 + SWZ(oc * 2, row)) = b1(acc[mt][r] + bias);
                    }
            }
        }
        __syncthreads();
        {
            bf16x8 a[4][4];
            #pragma unroll
            for (int mt = 0; mt < 4; ++mt)
                #pragma unroll
                for (int kk = 0; kk < 4; ++kk) {
                    int row = mt * 16 + lr;
                    a[mt][kk] = *(bf16x8*)(lds + SX + row * 256 + SWZ(g * 16 + kk * 64, row));
                }
            #pragma unroll
            for (int ntl = 0; ntl < 2; ++ntl) {
                const int oc = hb + ntl * 16 + lr;
                bf16x8 bfr[4];
                #pragma unroll
                for (int kk = 0; kk < 4; ++kk)
                    bfr[kk] = load_wfrag<false>(nullptr, wout, oc * 128 + kk * 32 + g * 8);
                f32x4 acc[4];
                #pragma unroll
                for (int mt = 0; mt < 4; ++mt) acc[mt] = f32x4{0.f, 0.f, 0.f, 0.f};
                #pragma unroll
                for (int kk = 0; kk < 4; ++kk)
                    #pragma unroll
                    for (int mt = 0; mt < 4; ++mt)
                        acc[mt] = __builtin_amdgcn_mfma_f32_16x16x32_bf16(a[mt][kk], bfr[kk], acc[mt], 0, 0, 0);
                const float bias = bout[oc];
                #pragma unroll
                for (int mt = 0; mt < 4; ++mt)
                    #pragma unroll
                    for (int r = 0; r < 4; ++r) {
                        const int row = mt * 16 + g * 4 + r;
                        if (row < 49) {
                            const size_t gi = base + (size_t)((row / 7) * 112 + (row % 7)) * 128 + oc;
                            out[gi] = x[gi] + acc[mt][r] + bias;
                        }
                    }
            }
        }
    }
}

} // namespace

extern "C" void kernel_launch(void* const* d_in, const int* in_sizes, int n_in,
                              void* d_out, int out_size, void* d_ws, size_t ws_size,
                              hipStream_t stream) {
    const float* x    = (const float*)d_in[0];
    const float* lng  = (const float*)d_in[1];
    const float* lnb  = (const float*)d_in[2];
    const float* wqkv = (const float*)d_in[3];
    const float* bqkv = (const float*)d_in[4];
    const float* wmo  = (const float*)d_in[5];
    const float* bmo  = (const float*)d_in[6];
    const float* wout = (const float*)d_in[7];
    const float* bout = (const float*)d_in[8];
    float* out = (float*)d_out;

    if (ws_size >= 133120) {
        unsigned short* wsb = (unsigned short*)d_ws;
        conv_w2<<<259, 256, 0, stream>>>(wqkv, bqkv, wmo, bmo, wout, bout, lng, lnb, wsb);
        swin_mfma<true><<<4096, 256, 0, stream>>>(x, lng, lnb, wqkv, bqkv, wmo, bmo,
                                                  wout, bout, wsb, out);
    } else {
        swin_mfma<false><<<4096, 256, 0, stream>>>(x, lng, lnb, wqkv, bqkv, wmo, bmo,
                                                   wout, bout, nullptr, out);
    }
}

// Round 10
// 116.101 us; speedup vs baseline: 1.4729x; 1.4729x over previous
//
#include <hip/hip_runtime.h>
#include <hip/hip_bf16.h>

namespace {

typedef __attribute__((ext_vector_type(8))) short bf16x8;
typedef __attribute__((ext_vector_type(4))) float f32x4;

union BF8U { unsigned u[4]; bf16x8 v; };

__device__ __forceinline__ unsigned pk2(float a, float b) {
    union { __hip_bfloat162 h2; unsigned u; } c;
    c.h2 = __float22bfloat162_rn(float2{a, b});
    return c.u;
}
__device__ __forceinline__ unsigned short b1(float f) {
    union { __hip_bfloat16 h; unsigned short s; } c;
    c.h = __float2bfloat16(f);
    return c.s;
}
__device__ __forceinline__ int SWZ(int byteoff, int row) {
    return byteoff ^ ((row & 7) << 4);
}

// LDS: two 16 KB tiles, rows = 64 x 256B (128 bf16), XOR-swizzled.
constexpr int SX  = 0;        // LN out; (fallback path reuses as MO-out)
constexpr int SAO = 16384;    // attention out [i][d]
constexpr int LDS_BYTES = 32768;

// Workspace layout (USEWS):
//   shorts [0, 49152)      : bf16 Wqkv' = wqkv * diag(ln_gamma)   [384][128]
//   shorts [49152, 65536)  : bf16 Wcomb = wout @ wmo              [128][128]
//   floats fb[0, 384)      : bqkv' = bqkv + wqkv @ ln_beta
//   floats fb[384, 512)    : bcomb = bout + wout @ bmo
// fb = (float*)(wsb + 65536); total bytes = 131072 + 2048 = 133120.

template<bool USEWS>
__device__ __forceinline__ bf16x8 load_wfrag(const unsigned short* wsb, const float* wf, int idx) {
    if constexpr (USEWS) {
        return *(const bf16x8*)(wsb + idx);
    } else {
        const float4 f0 = *(const float4*)(wf + idx);
        const float4 f1 = *(const float4*)(wf + idx + 4);
        bf16x8 r;
        r[0] = (short)b1(f0.x); r[1] = (short)b1(f0.y);
        r[2] = (short)b1(f0.z); r[3] = (short)b1(f0.w);
        r[4] = (short)b1(f1.x); r[5] = (short)b1(f1.y);
        r[6] = (short)b1(f1.z); r[7] = (short)b1(f1.w);
        return r;
    }
}

__global__ void conv_w2(const float* __restrict__ wqkv, const float* __restrict__ bqkv,
                        const float* __restrict__ wmo,  const float* __restrict__ bmo,
                        const float* __restrict__ wout, const float* __restrict__ bout,
                        const float* __restrict__ lng,  const float* __restrict__ lnb,
                        unsigned short* __restrict__ dst) {
    float* fb = (float*)(dst + 65536);
    const int bid = blockIdx.x, t = threadIdx.x;
    if (bid < 192) {
        const int idx = bid * 256 + t;
        dst[idx] = b1(wqkv[idx] * lng[idx & 127]);
    } else if (bid < 256) {
        const int e = (bid - 192) * 256 + t;
        const int o = e >> 7, i = e & 127;
        const float* wo = wout + o * 128;
        float s = 0.f;
        for (int k = 0; k < 128; ++k) s += wo[k] * wmo[k * 128 + i];
        dst[49152 + e] = b1(s);
    } else if (bid < 258) {
        const int o = (bid - 256) * 256 + t;
        if (o < 384) {
            const float* wr = wqkv + o * 128;
            float s = 0.f;
            for (int i = 0; i < 128; ++i) s += wr[i] * lnb[i];
            fb[o] = bqkv[o] + s;
        }
    } else {
        if (t < 128) {
            const float* wo = wout + t * 128;
            float s = 0.f;
            for (int k = 0; k < 128; ++k) s += wo[k] * bmo[k];
            fb[384 + t] = bout[t] + s;
        }
    }
}

template<bool USEWS>
__global__ __launch_bounds__(256, 4)
void swin_mfma(const float* __restrict__ x,
               const float* __restrict__ lng, const float* __restrict__ lnb,
               const float* __restrict__ wqkv, const float* __restrict__ bqkv,
               const float* __restrict__ wmo,  const float* __restrict__ bmo,
               const float* __restrict__ wout, const float* __restrict__ bout,
               const unsigned short* __restrict__ wsb,
               float* __restrict__ out)
{
    __shared__ char lds[LDS_BYTES];

    const float* fb = USEWS ? (const float*)(wsb + 65536) : nullptr;

    const int wid  = blockIdx.x;
    const int b    = wid >> 8;
    const int wh   = (wid >> 4) & 15;
    const int ww   = wid & 15;
    const int t    = threadIdx.x;
    const int lane = t & 63;
    const int h    = t >> 6;          // wave == head
    const int lr   = lane & 15;
    const int g    = lane >> 4;       // 0..3
    const int hb   = h * 32;

    const size_t base = ((size_t)(b * 112 + wh * 7) * 112 + ww * 7) * 128;

    // ================= LayerNorm (4 lanes per token) =================
    if (t < 240) *(f32x4*)(lds + SX + 49 * 256 + t * 16) = f32x4{0.f, 0.f, 0.f, 0.f};
    {
        const int tok = t >> 2, q4 = t & 3;
        if (tok < 49) {
            const float* xr = x + base + (size_t)((tok / 7) * 112 + (tok % 7)) * 128;
            float4 xv[8];
            float s1 = 0.f, s2 = 0.f;
            #pragma unroll
            for (int j = 0; j < 8; ++j) {
                xv[j] = *(const float4*)(xr + j * 16 + q4 * 4);
                s1 += xv[j].x + xv[j].y + xv[j].z + xv[j].w;
                s2 += xv[j].x * xv[j].x + xv[j].y * xv[j].y
                    + xv[j].z * xv[j].z + xv[j].w * xv[j].w;
            }
            s1 += __shfl_xor(s1, 1); s1 += __shfl_xor(s1, 2);
            s2 += __shfl_xor(s2, 1); s2 += __shfl_xor(s2, 2);
            const float mu  = s1 * (1.f / 128.f);
            const float inv = rsqrtf(s2 * (1.f / 128.f) - mu * mu + 1e-5f);
            #pragma unroll
            for (int j = 0; j < 8; ++j) {
                float y0, y1, y2, y3;
                if constexpr (USEWS) {
                    y0 = (xv[j].x - mu) * inv;
                    y1 = (xv[j].y - mu) * inv;
                    y2 = (xv[j].z - mu) * inv;
                    y3 = (xv[j].w - mu) * inv;
                } else {
                    const float4 gm = *(const float4*)(lng + j * 16 + q4 * 4);
                    const float4 bt = *(const float4*)(lnb + j * 16 + q4 * 4);
                    y0 = (xv[j].x - mu) * inv * gm.x + bt.x;
                    y1 = (xv[j].y - mu) * inv * gm.y + bt.y;
                    y2 = (xv[j].z - mu) * inv * gm.z + bt.z;
                    y3 = (xv[j].w - mu) * inv * gm.w + bt.w;
                }
                uint2 w; w.x = pk2(y0, y1); w.y = pk2(y2, y3);
                *(uint2*)(lds + SX + tok * 256 + SWZ(j * 32 + q4 * 8, tok)) = w;
            }
        }
    }
    __syncthreads();   // barrier #1

    // ---- in-wave redistribution: C-frag (idx on g*4+r, tiles) -> A/B-frag (idx on g*8+d) ----
    const int s01  = lr + ((lane & 16) ? 32 : 0);   // src lane for words 0,1
    const int s23  = s01 + 16;                      // src lane for words 2,3
    const bool hiT = (lane & 32) != 0;              // tile-parity select
    auto RD4 = [&](unsigned e0, unsigned e1, unsigned o0, unsigned o1) -> bf16x8 {
        BF8U r;
        const unsigned v0 = hiT ? o0 : e0;
        const unsigned v1 = hiT ? o1 : e1;
        r.u[0] = (unsigned)__shfl((int)v0, s01);
        r.u[1] = (unsigned)__shfl((int)v1, s01);
        r.u[2] = (unsigned)__shfl((int)v0, s23);
        r.u[3] = (unsigned)__shfl((int)v1, s23);
        return r.v;
    };

    // ============ Q pass: projection SWAPPED (D[o][token]) ============
    unsigned pkQ[4][2][2];   // [token-tile][o-tile][pair]
    {
        f32x4 aQ[2][4];
        #pragma unroll
        for (int ot = 0; ot < 2; ++ot)
            #pragma unroll
            for (int tt = 0; tt < 4; ++tt) aQ[ot][tt] = f32x4{0.f, 0.f, 0.f, 0.f};
        #pragma unroll
        for (int kk = 0; kk < 4; ++kk) {
            bf16x8 xa[4];
            #pragma unroll
            for (int tt = 0; tt < 4; ++tt) {
                int row = tt * 16 + lr;
                xa[tt] = *(bf16x8*)(lds + SX + row * 256 + SWZ(kk * 64 + g * 16, row));
            }
            #pragma unroll
            for (int ot = 0; ot < 2; ++ot) {
                bf16x8 wq = load_wfrag<USEWS>(wsb, wqkv, (hb + ot * 16 + lr) * 128 + kk * 32 + g * 8);
                #pragma unroll
                for (int tt = 0; tt < 4; ++tt)
                    aQ[ot][tt] = __builtin_amdgcn_mfma_f32_16x16x32_bf16(wq, xa[tt], aQ[ot][tt], 0, 0, 0);
            }
        }
        #pragma unroll
        for (int ot = 0; ot < 2; ++ot) {
            float4 bq;
            if constexpr (USEWS) bq = *(const float4*)(fb + hb + ot * 16 + g * 4);
            else                 bq = *(const float4*)(bqkv + hb + ot * 16 + g * 4);
            #pragma unroll
            for (int nti = 0; nti < 4; ++nti) {
                const float q0 = (aQ[ot][nti][0] + bq.x) * 0.17677669529663687f;
                const float q1 = (aQ[ot][nti][1] + bq.y) * 0.17677669529663687f;
                const float q2 = (aQ[ot][nti][2] + bq.z) * 0.17677669529663687f;
                const float q3 = (aQ[ot][nti][3] + bq.w) * 0.17677669529663687f;
                pkQ[nti][ot][0] = pk2(q0, q1); pkQ[nti][ot][1] = pk2(q2, q3);
            }
        }
    }
    asm volatile("" ::: "memory");

    // ============ K pass: projection SWAPPED (D[o][token]) ============
    unsigned pkK[4][2][2];
    {
        f32x4 aK[2][4];
        #pragma unroll
        for (int ot = 0; ot < 2; ++ot)
            #pragma unroll
            for (int tt = 0; tt < 4; ++tt) aK[ot][tt] = f32x4{0.f, 0.f, 0.f, 0.f};
        #pragma unroll
        for (int kk = 0; kk < 4; ++kk) {
            bf16x8 xa[4];
            #pragma unroll
            for (int tt = 0; tt < 4; ++tt) {
                int row = tt * 16 + lr;
                xa[tt] = *(bf16x8*)(lds + SX + row * 256 + SWZ(kk * 64 + g * 16, row));
            }
            #pragma unroll
            for (int ot = 0; ot < 2; ++ot) {
                bf16x8 wk = load_wfrag<USEWS>(wsb, wqkv, (128 + hb + ot * 16 + lr) * 128 + kk * 32 + g * 8);
                #pragma unroll
                for (int tt = 0; tt < 4; ++tt)
                    aK[ot][tt] = __builtin_amdgcn_mfma_f32_16x16x32_bf16(wk, xa[tt], aK[ot][tt], 0, 0, 0);
            }
        }
        #pragma unroll
        for (int ot = 0; ot < 2; ++ot) {
            float4 bk;
            if constexpr (USEWS) bk = *(const float4*)(fb + 128 + hb + ot * 16 + g * 4);
            else                 bk = *(const float4*)(bqkv + 128 + hb + ot * 16 + g * 4);
            #pragma unroll
            for (int nti = 0; nti < 4; ++nti) {
                pkK[nti][ot][0] = pk2(aK[ot][nti][0] + bk.x, aK[ot][nti][1] + bk.y);
                pkK[nti][ot][1] = pk2(aK[ot][nti][2] + bk.z, aK[ot][nti][3] + bk.w);
            }
        }
    }
    asm volatile("" ::: "memory");

    // ============ scores S[j][i] = mfma(K, Q) + softmax, i-tiles in 2 halves ============
    unsigned pkP[4][4][2];   // [i-tile][j-tile][pair]
    #pragma unroll
    for (int half = 0; half < 2; ++half) {
        f32x4 S[4][2];   // [j-tile][i-within-half]
        bf16x8 qb[2];
        #pragma unroll
        for (int ni = 0; ni < 2; ++ni) {
            const int nti = half * 2 + ni;
            qb[ni] = RD4(pkQ[nti][0][0], pkQ[nti][0][1], pkQ[nti][1][0], pkQ[nti][1][1]);
        }
        #pragma unroll
        for (int mtj = 0; mtj < 4; ++mtj) {
            bf16x8 ka = RD4(pkK[mtj][0][0], pkK[mtj][0][1], pkK[mtj][1][0], pkK[mtj][1][1]);
            #pragma unroll
            for (int ni = 0; ni < 2; ++ni)
                S[mtj][ni] = __builtin_amdgcn_mfma_f32_16x16x32_bf16(ka, qb[ni],
                                                                     f32x4{0.f, 0.f, 0.f, 0.f}, 0, 0, 0);
        }
        // mask keys j >= 49 (j = 48 + g*4 + r in tile 3)
        #pragma unroll
        for (int ni = 0; ni < 2; ++ni)
            #pragma unroll
            for (int r = 0; r < 4; ++r)
                if (r != 0 || g != 0) S[3][ni][r] = -1e30f;

        #pragma unroll
        for (int ni = 0; ni < 2; ++ni) {
            const int nti = half * 2 + ni;
            float m = S[0][ni][0];
            #pragma unroll
            for (int mtj = 0; mtj < 4; ++mtj)
                #pragma unroll
                for (int r = 0; r < 4; ++r) m = fmaxf(m, S[mtj][ni][r]);
            m = fmaxf(m, __shfl_xor(m, 16));
            m = fmaxf(m, __shfl_xor(m, 32));
            float sum = 0.f;
            #pragma unroll
            for (int mtj = 0; mtj < 4; ++mtj)
                #pragma unroll
                for (int r = 0; r < 4; ++r) {
                    const float p = __expf(S[mtj][ni][r] - m);
                    S[mtj][ni][r] = p;
                    sum += p;
                }
            sum += __shfl_xor(sum, 16);
            sum += __shfl_xor(sum, 32);
            const float rinv = 1.0f / sum;
            #pragma unroll
            for (int mtj = 0; mtj < 4; ++mtj) {
                pkP[nti][mtj][0] = pk2(S[mtj][ni][0] * rinv, S[mtj][ni][1] * rinv);
                pkP[nti][mtj][1] = pk2(S[mtj][ni][2] * rinv, S[mtj][ni][3] * rinv);
            }
        }
    }
    asm volatile("" ::: "memory");

    // ============ V pass: projection NORMAL (D[token][o]) ============
    unsigned pkV[2][4][2];   // [d-tile][token-tile][pair]
    {
        f32x4 aV[4][2];
        #pragma unroll
        for (int mt = 0; mt < 4; ++mt) {
            aV[mt][0] = f32x4{0.f, 0.f, 0.f, 0.f};
            aV[mt][1] = f32x4{0.f, 0.f, 0.f, 0.f};
        }
        #pragma unroll
        for (int kk = 0; kk < 4; ++kk) {
            bf16x8 xa[4];
            #pragma unroll
            for (int tt = 0; tt < 4; ++tt) {
                int row = tt * 16 + lr;
                xa[tt] = *(bf16x8*)(lds + SX + row * 256 + SWZ(kk * 64 + g * 16, row));
            }
            bf16x8 wv0 = load_wfrag<USEWS>(wsb, wqkv, (256 + hb + lr) * 128 + kk * 32 + g * 8);
            bf16x8 wv1 = load_wfrag<USEWS>(wsb, wqkv, (256 + hb + 16 + lr) * 128 + kk * 32 + g * 8);
            #pragma unroll
            for (int mt = 0; mt < 4; ++mt) {
                aV[mt][0] = __builtin_amdgcn_mfma_f32_16x16x32_bf16(xa[mt], wv0, aV[mt][0], 0, 0, 0);
                aV[mt][1] = __builtin_amdgcn_mfma_f32_16x16x32_bf16(xa[mt], wv1, aV[mt][1], 0, 0, 0);
            }
        }
        const float bv0 = USEWS ? fb[256 + hb + lr]      : bqkv[256 + hb + lr];
        const float bv1 = USEWS ? fb[256 + hb + 16 + lr] : bqkv[256 + hb + 16 + lr];
        #pragma unroll
        for (int mt = 0; mt < 4; ++mt) {
            pkV[0][mt][0] = pk2(aV[mt][0][0] + bv0, aV[mt][0][1] + bv0);
            pkV[0][mt][1] = pk2(aV[mt][0][2] + bv0, aV[mt][0][3] + bv0);
            pkV[1][mt][0] = pk2(aV[mt][1][0] + bv1, aV[mt][1][1] + bv1);
            pkV[1][mt][1] = pk2(aV[mt][1][2] + bv1, aV[mt][1][3] + bv1);
        }
    }
    asm volatile("" ::: "memory");

    // ============ PV (swapped): O[d][i] = mfma(V, P), coalesced uint2 O-writes ============
    {
        bf16x8 vb[2][2];   // [kk][d-tile]; as A-frag: row-lane=d, k=j
        #pragma unroll
        for (int kk = 0; kk < 2; ++kk)
            #pragma unroll
            for (int ntd = 0; ntd < 2; ++ntd)
                vb[kk][ntd] = RD4(pkV[ntd][2 * kk][0], pkV[ntd][2 * kk][1],
                                  pkV[ntd][2 * kk + 1][0], pkV[ntd][2 * kk + 1][1]);
        #pragma unroll
        for (int nti = 0; nti < 4; ++nti) {
            bf16x8 pa0 = RD4(pkP[nti][0][0], pkP[nti][0][1], pkP[nti][1][0], pkP[nti][1][1]);
            bf16x8 pa1 = RD4(pkP[nti][2][0], pkP[nti][2][1], pkP[nti][3][0], pkP[nti][3][1]);
            f32x4 O0 = f32x4{0.f, 0.f, 0.f, 0.f}, O1 = O0;
            O0 = __builtin_amdgcn_mfma_f32_16x16x32_bf16(vb[0][0], pa0, O0, 0, 0, 0);
            O0 = __builtin_amdgcn_mfma_f32_16x16x32_bf16(vb[1][0], pa1, O0, 0, 0, 0);
            O1 = __builtin_amdgcn_mfma_f32_16x16x32_bf16(vb[0][1], pa0, O1, 0, 0, 0);
            O1 = __builtin_amdgcn_mfma_f32_16x16x32_bf16(vb[1][1], pa1, O1, 0, 0, 0);
            const int i = nti * 16 + lr;
            uint2 w0, w1;
            w0.x = pk2(O0[0], O0[1]); w0.y = pk2(O0[2], O0[3]);
            w1.x = pk2(O1[0], O1[1]); w1.y = pk2(O1[2], O1[3]);
            *(uint2*)(lds + SAO + i * 256 + SWZ((hb + g * 4) * 2, i))      = w0;
            *(uint2*)(lds + SAO + i * 256 + SWZ((hb + 16 + g * 4) * 2, i)) = w1;
        }
    }
    __syncthreads();   // barrier #2

    if constexpr (USEWS) {
        // ============ fused (MO∘OUT) projection + residual, kk-outer ============
        f32x4 acc[4][2];
        #pragma unroll
        for (int mt = 0; mt < 4; ++mt) {
            acc[mt][0] = f32x4{0.f, 0.f, 0.f, 0.f};
            acc[mt][1] = f32x4{0.f, 0.f, 0.f, 0.f};
        }
        #pragma unroll
        for (int kk = 0; kk < 4; ++kk) {
            bf16x8 a4[4];
            #pragma unroll
            for (int mt = 0; mt < 4; ++mt) {
                int row = mt * 16 + lr;
                a4[mt] = *(bf16x8*)(lds + SAO + row * 256 + SWZ(g * 16 + kk * 64, row));
            }
            bf16x8 b0 = *(const bf16x8*)(wsb + 49152 + (hb + lr) * 128 + kk * 32 + g * 8);
            bf16x8 b1f = *(const bf16x8*)(wsb + 49152 + (hb + 16 + lr) * 128 + kk * 32 + g * 8);
            #pragma unroll
            for (int mt = 0; mt < 4; ++mt) {
                acc[mt][0] = __builtin_amdgcn_mfma_f32_16x16x32_bf16(a4[mt], b0,  acc[mt][0], 0, 0, 0);
                acc[mt][1] = __builtin_amdgcn_mfma_f32_16x16x32_bf16(a4[mt], b1f, acc[mt][1], 0, 0, 0);
            }
        }
        #pragma unroll
        for (int ntl = 0; ntl < 2; ++ntl) {
            const int oc = hb + ntl * 16 + lr;
            const float bias = fb[384 + oc];
            #pragma unroll
            for (int mt = 0; mt < 4; ++mt)
                #pragma unroll
                for (int r = 0; r < 4; ++r) {
                    const int row = mt * 16 + g * 4 + r;
                    if (row < 49) {
                        const size_t gi = base + (size_t)((row / 7) * 112 + (row % 7)) * 128 + oc;
                        out[gi] = x[gi] + acc[mt][ntl][r] + bias;
                    }
                }
        }
    } else {
        // ============ fallback: MO projection -> SX, barrier, OUT + residual ============
        {
            bf16x8 a[4][4];
            #pragma unroll
            for (int mt = 0; mt < 4; ++mt)
                #pragma unroll
                for (int kk = 0; kk < 4; ++kk) {
                    int row = mt * 16 + lr;
                    a[mt][kk] = *(bf16x8*)(lds + SAO + row * 256 + SWZ(g * 16 + kk * 64, row));
                }
            #pragma unroll
            for (int ntl = 0; ntl < 2; ++ntl) {
                const int oc = hb + ntl * 16 + lr;
                bf16x8 bfr[4];
                #pragma unroll
                for (int kk = 0; kk < 4; ++kk)
                    bfr[kk] = load_wfrag<false>(nullptr, wmo, oc * 128 + kk * 32 + g * 8);
                f32x4 acc[4];
                #pragma unroll
                for (int mt = 0; mt < 4; ++mt) acc[mt] = f32x4{0.f, 0.f, 0.f, 0.f};
                #pragma unroll
                for (int kk = 0; kk < 4; ++kk)
                    #pragma unroll
                    for (int mt = 0; mt < 4; ++mt)
                        acc[mt] = __builtin_amdgcn_mfma_f32_16x16x32_bf16(a[mt][kk], bfr[kk], acc[mt], 0, 0, 0);
                const float bias = bmo[oc];
                #pragma unroll
                for (int mt = 0; mt < 4; ++mt)
                    #pragma unroll
                    for (int r = 0; r < 4; ++r) {
                        int row = mt * 16 + g * 4 + r;
                        *(unsigned short*)(lds + SX + row * 256 + SWZ(oc * 2, row)) = b1(acc[mt][r] + bias);
                    }
            }
        }
        __syncthreads();
        {
            bf16x8 a[4][4];
            #pragma unroll
            for (int mt = 0; mt < 4; ++mt)
                #pragma unroll
                for (int kk = 0; kk < 4; ++kk) {
                    int row = mt * 16 + lr;
                    a[mt][kk] = *(bf16x8*)(lds + SX + row * 256 + SWZ(g * 16 + kk * 64, row));
                }
            #pragma unroll
            for (int ntl = 0; ntl < 2; ++ntl) {
                const int oc = hb + ntl * 16 + lr;
                bf16x8 bfr[4];
                #pragma unroll
                for (int kk = 0; kk < 4; ++kk)
                    bfr[kk] = load_wfrag<false>(nullptr, wout, oc * 128 + kk * 32 + g * 8);
                f32x4 acc[4];
                #pragma unroll
                for (int mt = 0; mt < 4; ++mt) acc[mt] = f32x4{0.f, 0.f, 0.f, 0.f};
                #pragma unroll
                for (int kk = 0; kk < 4; ++kk)
                    #pragma unroll
                    for (int mt = 0; mt < 4; ++mt)
                        acc[mt] = __builtin_amdgcn_mfma_f32_16x16x32_bf16(a[mt][kk], bfr[kk], acc[mt], 0, 0, 0);
                const float bias = bout[oc];
                #pragma unroll
                for (int mt = 0; mt < 4; ++mt)
                    #pragma unroll
                    for (int r = 0; r < 4; ++r) {
                        const int row = mt * 16 + g * 4 + r;
                        if (row < 49) {
                            const size_t gi = base + (size_t)((row / 7) * 112 + (row % 7)) * 128 + oc;
                            out[gi] = x[gi] + acc[mt][r] + bias;
                        }
                    }
            }
        }
    }
}

} // namespace

extern "C" void kernel_launch(void* const* d_in, const int* in_sizes, int n_in,
                              void* d_out, int out_size, void* d_ws, size_t ws_size,
                              hipStream_t stream) {
    const float* x    = (const float*)d_in[0];
    const float* lng  = (const float*)d_in[1];
    const float* lnb  = (const float*)d_in[2];
    const float* wqkv = (const float*)d_in[3];
    const float* bqkv = (const float*)d_in[4];
    const float* wmo  = (const float*)d_in[5];
    const float* bmo  = (const float*)d_in[6];
    const float* wout = (const float*)d_in[7];
    const float* bout = (const float*)d_in[8];
    float* out = (float*)d_out;

    if (ws_size >= 133120) {
        unsigned short* wsb = (unsigned short*)d_ws;
        conv_w2<<<259, 256, 0, stream>>>(wqkv, bqkv, wmo, bmo, wout, bout, lng, lnb, wsb);
        swin_mfma<true><<<4096, 256, 0, stream>>>(x, lng, lnb, wqkv, bqkv, wmo, bmo,
                                                  wout, bout, wsb, out);
    } else {
        swin_mfma<false><<<4096, 256, 0, stream>>>(x, lng, lnb, wqkv, bqkv, wmo, bmo,
                                                   wout, bout, nullptr, out);
    }
}

// Round 11
// 102.893 us; speedup vs baseline: 1.6619x; 1.1284x over previous
//
#include <hip/hip_runtime.h>
#include <hip/hip_bf16.h>

namespace {

typedef __attribute__((ext_vector_type(8))) short bf16x8;
typedef __attribute__((ext_vector_type(4))) float f32x4;

union BF8U { unsigned u[4]; bf16x8 v; };

__device__ __forceinline__ unsigned pk2(float a, float b) {
    union { __hip_bfloat162 h2; unsigned u; } c;
    c.h2 = __float22bfloat162_rn(float2{a, b});
    return c.u;
}
__device__ __forceinline__ unsigned short b1(float f) {
    union { __hip_bfloat16 h; unsigned short s; } c;
    c.h = __float2bfloat16(f);
    return c.s;
}
__device__ __forceinline__ int SWZ(int byteoff, int row) {
    return byteoff ^ ((row & 7) << 4);
}

// LDS: two 16 KB tiles, rows = 64 x 256B (128 bf16), XOR-swizzled.
constexpr int SX  = 0;        // LN out; (fallback path reuses as MO-out)
constexpr int SAO = 16384;    // attention out [i][d]
constexpr int LDS_BYTES = 32768;

// Workspace layout (USEWS):
//   shorts [0, 49152)      : bf16 Wqkv' = wqkv * diag(ln_gamma)   [384][128]
//   shorts [49152, 65536)  : bf16 Wcomb = wout @ wmo              [128][128]
//   floats fb[0, 384)      : bqkv' = bqkv + wqkv @ ln_beta
//   floats fb[384, 512)    : bcomb = bout + wout @ bmo
// fb = (float*)(wsb + 65536); total bytes = 131072 + 2048 = 133120.

template<bool USEWS>
__device__ __forceinline__ bf16x8 load_wfrag(const unsigned short* wsb, const float* wf, int idx) {
    if constexpr (USEWS) {
        return *(const bf16x8*)(wsb + idx);
    } else {
        const float4 f0 = *(const float4*)(wf + idx);
        const float4 f1 = *(const float4*)(wf + idx + 4);
        bf16x8 r;
        r[0] = (short)b1(f0.x); r[1] = (short)b1(f0.y);
        r[2] = (short)b1(f0.z); r[3] = (short)b1(f0.w);
        r[4] = (short)b1(f1.x); r[5] = (short)b1(f1.y);
        r[6] = (short)b1(f1.z); r[7] = (short)b1(f1.w);
        return r;
    }
}

__global__ void conv_w2(const float* __restrict__ wqkv, const float* __restrict__ bqkv,
                        const float* __restrict__ wmo,  const float* __restrict__ bmo,
                        const float* __restrict__ wout, const float* __restrict__ bout,
                        const float* __restrict__ lng,  const float* __restrict__ lnb,
                        unsigned short* __restrict__ dst) {
    float* fb = (float*)(dst + 65536);
    const int bid = blockIdx.x, t = threadIdx.x;
    if (bid < 192) {
        const int idx = bid * 256 + t;
        dst[idx] = b1(wqkv[idx] * lng[idx & 127]);
    } else if (bid < 256) {
        const int e = (bid - 192) * 256 + t;
        const int o = e >> 7, i = e & 127;
        const float* wo = wout + o * 128;
        float s = 0.f;
        for (int k = 0; k < 128; ++k) s += wo[k] * wmo[k * 128 + i];
        dst[49152 + e] = b1(s);
    } else if (bid < 258) {
        const int o = (bid - 256) * 256 + t;
        if (o < 384) {
            const float* wr = wqkv + o * 128;
            float s = 0.f;
            for (int i = 0; i < 128; ++i) s += wr[i] * lnb[i];
            fb[o] = bqkv[o] + s;
        }
    } else {
        if (t < 128) {
            const float* wo = wout + t * 128;
            float s = 0.f;
            for (int k = 0; k < 128; ++k) s += wo[k] * bmo[k];
            fb[384 + t] = bout[t] + s;
        }
    }
}

template<bool USEWS>
__global__ __launch_bounds__(256, 4)
void swin_mfma(const float* __restrict__ x,
               const float* __restrict__ lng, const float* __restrict__ lnb,
               const float* __restrict__ wqkv, const float* __restrict__ bqkv,
               const float* __restrict__ wmo,  const float* __restrict__ bmo,
               const float* __restrict__ wout, const float* __restrict__ bout,
               const unsigned short* __restrict__ wsb,
               float* __restrict__ out)
{
    __shared__ char lds[LDS_BYTES];

    const float* fb = USEWS ? (const float*)(wsb + 65536) : nullptr;

    const int wid  = blockIdx.x;
    const int b    = wid >> 8;
    const int wh   = (wid >> 4) & 15;
    const int ww   = wid & 15;
    const int t    = threadIdx.x;
    const int lane = t & 63;
    const int h    = t >> 6;          // wave == head
    const int lr   = lane & 15;
    const int g    = lane >> 4;       // 0..3
    const int hb   = h * 32;

    const size_t base = ((size_t)(b * 112 + wh * 7) * 112 + ww * 7) * 128;

    // ================= LayerNorm (4 lanes per token) =================
    if (t < 240) *(f32x4*)(lds + SX + 49 * 256 + t * 16) = f32x4{0.f, 0.f, 0.f, 0.f};
    {
        const int tok = t >> 2, q4 = t & 3;
        if (tok < 49) {
            const float* xr = x + base + (size_t)((tok / 7) * 112 + (tok % 7)) * 128;
            float4 xv[8];
            float s1 = 0.f, s2 = 0.f;
            #pragma unroll
            for (int j = 0; j < 8; ++j) {
                xv[j] = *(const float4*)(xr + j * 16 + q4 * 4);
                s1 += xv[j].x + xv[j].y + xv[j].z + xv[j].w;
                s2 += xv[j].x * xv[j].x + xv[j].y * xv[j].y
                    + xv[j].z * xv[j].z + xv[j].w * xv[j].w;
            }
            s1 += __shfl_xor(s1, 1); s1 += __shfl_xor(s1, 2);
            s2 += __shfl_xor(s2, 1); s2 += __shfl_xor(s2, 2);
            const float mu  = s1 * (1.f / 128.f);
            const float inv = rsqrtf(s2 * (1.f / 128.f) - mu * mu + 1e-5f);
            #pragma unroll
            for (int j = 0; j < 8; ++j) {
                float y0, y1, y2, y3;
                if constexpr (USEWS) {
                    y0 = (xv[j].x - mu) * inv;
                    y1 = (xv[j].y - mu) * inv;
                    y2 = (xv[j].z - mu) * inv;
                    y3 = (xv[j].w - mu) * inv;
                } else {
                    const float4 gm = *(const float4*)(lng + j * 16 + q4 * 4);
                    const float4 bt = *(const float4*)(lnb + j * 16 + q4 * 4);
                    y0 = (xv[j].x - mu) * inv * gm.x + bt.x;
                    y1 = (xv[j].y - mu) * inv * gm.y + bt.y;
                    y2 = (xv[j].z - mu) * inv * gm.z + bt.z;
                    y3 = (xv[j].w - mu) * inv * gm.w + bt.w;
                }
                uint2 w; w.x = pk2(y0, y1); w.y = pk2(y2, y3);
                *(uint2*)(lds + SX + tok * 256 + SWZ(j * 32 + q4 * 8, tok)) = w;
            }
        }
    }
    __syncthreads();   // barrier #1

    // ---- in-wave redistribution: C-frag (idx on g*4+r, tiles) -> A/B-frag (idx on g*8+d) ----
    const int s01  = lr + ((lane & 16) ? 32 : 0);   // src lane for words 0,1
    const int s23  = s01 + 16;                      // src lane for words 2,3
    const bool hiT = (lane & 32) != 0;              // tile-parity select
    auto RD4 = [&](unsigned e0, unsigned e1, unsigned o0, unsigned o1) -> bf16x8 {
        BF8U r;
        const unsigned v0 = hiT ? o0 : e0;
        const unsigned v1 = hiT ? o1 : e1;
        r.u[0] = (unsigned)__shfl((int)v0, s01);
        r.u[1] = (unsigned)__shfl((int)v1, s01);
        r.u[2] = (unsigned)__shfl((int)v0, s23);
        r.u[3] = (unsigned)__shfl((int)v1, s23);
        return r.v;
    };

    // ============ Q pass: projection SWAPPED (D[o][token]) ============
    unsigned pkQ[4][2][2];   // [token-tile][o-tile][pair]
    {
        f32x4 aQ[2][4];
        #pragma unroll
        for (int ot = 0; ot < 2; ++ot)
            #pragma unroll
            for (int tt = 0; tt < 4; ++tt) aQ[ot][tt] = f32x4{0.f, 0.f, 0.f, 0.f};
        #pragma unroll
        for (int kk = 0; kk < 4; ++kk) {
            bf16x8 xa[4];
            #pragma unroll
            for (int tt = 0; tt < 4; ++tt) {
                int row = tt * 16 + lr;
                xa[tt] = *(bf16x8*)(lds + SX + row * 256 + SWZ(kk * 64 + g * 16, row));
            }
            #pragma unroll
            for (int ot = 0; ot < 2; ++ot) {
                bf16x8 wq = load_wfrag<USEWS>(wsb, wqkv, (hb + ot * 16 + lr) * 128 + kk * 32 + g * 8);
                __builtin_amdgcn_s_setprio(1);
                #pragma unroll
                for (int tt = 0; tt < 4; ++tt)
                    aQ[ot][tt] = __builtin_amdgcn_mfma_f32_16x16x32_bf16(wq, xa[tt], aQ[ot][tt], 0, 0, 0);
                __builtin_amdgcn_s_setprio(0);
            }
        }
        #pragma unroll
        for (int ot = 0; ot < 2; ++ot) {
            float4 bq;
            if constexpr (USEWS) bq = *(const float4*)(fb + hb + ot * 16 + g * 4);
            else                 bq = *(const float4*)(bqkv + hb + ot * 16 + g * 4);
            #pragma unroll
            for (int nti = 0; nti < 4; ++nti) {
                const float q0 = (aQ[ot][nti][0] + bq.x) * 0.17677669529663687f;
                const float q1 = (aQ[ot][nti][1] + bq.y) * 0.17677669529663687f;
                const float q2 = (aQ[ot][nti][2] + bq.z) * 0.17677669529663687f;
                const float q3 = (aQ[ot][nti][3] + bq.w) * 0.17677669529663687f;
                pkQ[nti][ot][0] = pk2(q0, q1); pkQ[nti][ot][1] = pk2(q2, q3);
            }
        }
    }
    asm volatile("" ::: "memory");

    // ============ K pass: projection SWAPPED (D[o][token]) ============
    unsigned pkK[4][2][2];
    {
        f32x4 aK[2][4];
        #pragma unroll
        for (int ot = 0; ot < 2; ++ot)
            #pragma unroll
            for (int tt = 0; tt < 4; ++tt) aK[ot][tt] = f32x4{0.f, 0.f, 0.f, 0.f};
        #pragma unroll
        for (int kk = 0; kk < 4; ++kk) {
            bf16x8 xa[4];
            #pragma unroll
            for (int tt = 0; tt < 4; ++tt) {
                int row = tt * 16 + lr;
                xa[tt] = *(bf16x8*)(lds + SX + row * 256 + SWZ(kk * 64 + g * 16, row));
            }
            #pragma unroll
            for (int ot = 0; ot < 2; ++ot) {
                bf16x8 wk = load_wfrag<USEWS>(wsb, wqkv, (128 + hb + ot * 16 + lr) * 128 + kk * 32 + g * 8);
                __builtin_amdgcn_s_setprio(1);
                #pragma unroll
                for (int tt = 0; tt < 4; ++tt)
                    aK[ot][tt] = __builtin_amdgcn_mfma_f32_16x16x32_bf16(wk, xa[tt], aK[ot][tt], 0, 0, 0);
                __builtin_amdgcn_s_setprio(0);
            }
        }
        #pragma unroll
        for (int ot = 0; ot < 2; ++ot) {
            float4 bk;
            if constexpr (USEWS) bk = *(const float4*)(fb + 128 + hb + ot * 16 + g * 4);
            else                 bk = *(const float4*)(bqkv + 128 + hb + ot * 16 + g * 4);
            #pragma unroll
            for (int nti = 0; nti < 4; ++nti) {
                pkK[nti][ot][0] = pk2(aK[ot][nti][0] + bk.x, aK[ot][nti][1] + bk.y);
                pkK[nti][ot][1] = pk2(aK[ot][nti][2] + bk.z, aK[ot][nti][3] + bk.w);
            }
        }
    }
    asm volatile("" ::: "memory");

    // ============ scores S[j][i] = mfma(K, Q) + softmax, i-tiles in 2 halves ============
    unsigned pkP[4][4][2];   // [i-tile][j-tile][pair]
    #pragma unroll
    for (int half = 0; half < 2; ++half) {
        f32x4 S[4][2];   // [j-tile][i-within-half]
        bf16x8 qb[2];
        #pragma unroll
        for (int ni = 0; ni < 2; ++ni) {
            const int nti = half * 2 + ni;
            qb[ni] = RD4(pkQ[nti][0][0], pkQ[nti][0][1], pkQ[nti][1][0], pkQ[nti][1][1]);
        }
        #pragma unroll
        for (int mtj = 0; mtj < 4; ++mtj) {
            bf16x8 ka = RD4(pkK[mtj][0][0], pkK[mtj][0][1], pkK[mtj][1][0], pkK[mtj][1][1]);
            __builtin_amdgcn_s_setprio(1);
            #pragma unroll
            for (int ni = 0; ni < 2; ++ni)
                S[mtj][ni] = __builtin_amdgcn_mfma_f32_16x16x32_bf16(ka, qb[ni],
                                                                     f32x4{0.f, 0.f, 0.f, 0.f}, 0, 0, 0);
            __builtin_amdgcn_s_setprio(0);
        }
        // mask keys j >= 49 (j = 48 + g*4 + r in tile 3)
        #pragma unroll
        for (int ni = 0; ni < 2; ++ni)
            #pragma unroll
            for (int r = 0; r < 4; ++r)
                if (r != 0 || g != 0) S[3][ni][r] = -1e30f;

        #pragma unroll
        for (int ni = 0; ni < 2; ++ni) {
            const int nti = half * 2 + ni;
            float m = S[0][ni][0];
            #pragma unroll
            for (int mtj = 0; mtj < 4; ++mtj)
                #pragma unroll
                for (int r = 0; r < 4; ++r) m = fmaxf(m, S[mtj][ni][r]);
            m = fmaxf(m, __shfl_xor(m, 16));
            m = fmaxf(m, __shfl_xor(m, 32));
            float sum = 0.f;
            #pragma unroll
            for (int mtj = 0; mtj < 4; ++mtj)
                #pragma unroll
                for (int r = 0; r < 4; ++r) {
                    const float p = __expf(S[mtj][ni][r] - m);
                    S[mtj][ni][r] = p;
                    sum += p;
                }
            sum += __shfl_xor(sum, 16);
            sum += __shfl_xor(sum, 32);
            const float rinv = 1.0f / sum;
            #pragma unroll
            for (int mtj = 0; mtj < 4; ++mtj) {
                pkP[nti][mtj][0] = pk2(S[mtj][ni][0] * rinv, S[mtj][ni][1] * rinv);
                pkP[nti][mtj][1] = pk2(S[mtj][ni][2] * rinv, S[mtj][ni][3] * rinv);
            }
        }
    }
    // NOTE: no scheduling fence here — let V-pass weight loads issue under softmax.

    // ============ V pass: projection NORMAL (D[token][o]) ============
    unsigned pkV[2][4][2];   // [d-tile][token-tile][pair]
    {
        f32x4 aV[4][2];
        #pragma unroll
        for (int mt = 0; mt < 4; ++mt) {
            aV[mt][0] = f32x4{0.f, 0.f, 0.f, 0.f};
            aV[mt][1] = f32x4{0.f, 0.f, 0.f, 0.f};
        }
        #pragma unroll
        for (int kk = 0; kk < 4; ++kk) {
            bf16x8 xa[4];
            #pragma unroll
            for (int tt = 0; tt < 4; ++tt) {
                int row = tt * 16 + lr;
                xa[tt] = *(bf16x8*)(lds + SX + row * 256 + SWZ(kk * 64 + g * 16, row));
            }
            bf16x8 wv0 = load_wfrag<USEWS>(wsb, wqkv, (256 + hb + lr) * 128 + kk * 32 + g * 8);
            bf16x8 wv1 = load_wfrag<USEWS>(wsb, wqkv, (256 + hb + 16 + lr) * 128 + kk * 32 + g * 8);
            __builtin_amdgcn_s_setprio(1);
            #pragma unroll
            for (int mt = 0; mt < 4; ++mt) {
                aV[mt][0] = __builtin_amdgcn_mfma_f32_16x16x32_bf16(xa[mt], wv0, aV[mt][0], 0, 0, 0);
                aV[mt][1] = __builtin_amdgcn_mfma_f32_16x16x32_bf16(xa[mt], wv1, aV[mt][1], 0, 0, 0);
            }
            __builtin_amdgcn_s_setprio(0);
        }
        const float bv0 = USEWS ? fb[256 + hb + lr]      : bqkv[256 + hb + lr];
        const float bv1 = USEWS ? fb[256 + hb + 16 + lr] : bqkv[256 + hb + 16 + lr];
        #pragma unroll
        for (int mt = 0; mt < 4; ++mt) {
            pkV[0][mt][0] = pk2(aV[mt][0][0] + bv0, aV[mt][0][1] + bv0);
            pkV[0][mt][1] = pk2(aV[mt][0][2] + bv0, aV[mt][0][3] + bv0);
            pkV[1][mt][0] = pk2(aV[mt][1][0] + bv1, aV[mt][1][1] + bv1);
            pkV[1][mt][1] = pk2(aV[mt][1][2] + bv1, aV[mt][1][3] + bv1);
        }
    }
    asm volatile("" ::: "memory");

    // ============ PV: O = P @ V ============
    {
        bf16x8 vb[2][2];   // [kk][d-tile]
        #pragma unroll
        for (int kk = 0; kk < 2; ++kk)
            #pragma unroll
            for (int ntd = 0; ntd < 2; ++ntd)
                vb[kk][ntd] = RD4(pkV[ntd][2 * kk][0], pkV[ntd][2 * kk][1],
                                  pkV[ntd][2 * kk + 1][0], pkV[ntd][2 * kk + 1][1]);
        #pragma unroll
        for (int mti = 0; mti < 4; ++mti) {
            bf16x8 pa0 = RD4(pkP[mti][0][0], pkP[mti][0][1], pkP[mti][1][0], pkP[mti][1][1]);
            bf16x8 pa1 = RD4(pkP[mti][2][0], pkP[mti][2][1], pkP[mti][3][0], pkP[mti][3][1]);
            f32x4 O0 = f32x4{0.f, 0.f, 0.f, 0.f}, O1 = O0;
            __builtin_amdgcn_s_setprio(1);
            O0 = __builtin_amdgcn_mfma_f32_16x16x32_bf16(pa0, vb[0][0], O0, 0, 0, 0);
            O0 = __builtin_amdgcn_mfma_f32_16x16x32_bf16(pa1, vb[1][0], O0, 0, 0, 0);
            O1 = __builtin_amdgcn_mfma_f32_16x16x32_bf16(pa0, vb[0][1], O1, 0, 0, 0);
            O1 = __builtin_amdgcn_mfma_f32_16x16x32_bf16(pa1, vb[1][1], O1, 0, 0, 0);
            __builtin_amdgcn_s_setprio(0);
            #pragma unroll
            for (int r = 0; r < 4; ++r) {
                const int i = mti * 16 + g * 4 + r;
                *(unsigned short*)(lds + SAO + i * 256 + SWZ((hb + lr) * 2, i))      = b1(O0[r]);
                *(unsigned short*)(lds + SAO + i * 256 + SWZ((hb + 16 + lr) * 2, i)) = b1(O1[r]);
            }
        }
    }
    __syncthreads();   // barrier #2

    if constexpr (USEWS) {
        // ============ fused (MO∘OUT) projection + residual, kk-outer ============
        f32x4 acc[4][2];
        #pragma unroll
        for (int mt = 0; mt < 4; ++mt) {
            acc[mt][0] = f32x4{0.f, 0.f, 0.f, 0.f};
            acc[mt][1] = f32x4{0.f, 0.f, 0.f, 0.f};
        }
        #pragma unroll
        for (int kk = 0; kk < 4; ++kk) {
            bf16x8 a4[4];
            #pragma unroll
            for (int mt = 0; mt < 4; ++mt) {
                int row = mt * 16 + lr;
                a4[mt] = *(bf16x8*)(lds + SAO + row * 256 + SWZ(g * 16 + kk * 64, row));
            }
            bf16x8 b0 = *(const bf16x8*)(wsb + 49152 + (hb + lr) * 128 + kk * 32 + g * 8);
            bf16x8 b1f = *(const bf16x8*)(wsb + 49152 + (hb + 16 + lr) * 128 + kk * 32 + g * 8);
            __builtin_amdgcn_s_setprio(1);
            #pragma unroll
            for (int mt = 0; mt < 4; ++mt) {
                acc[mt][0] = __builtin_amdgcn_mfma_f32_16x16x32_bf16(a4[mt], b0,  acc[mt][0], 0, 0, 0);
                acc[mt][1] = __builtin_amdgcn_mfma_f32_16x16x32_bf16(a4[mt], b1f, acc[mt][1], 0, 0, 0);
            }
            __builtin_amdgcn_s_setprio(0);
        }
        #pragma unroll
        for (int ntl = 0; ntl < 2; ++ntl) {
            const int oc = hb + ntl * 16 + lr;
            const float bias = fb[384 + oc];
            #pragma unroll
            for (int mt = 0; mt < 4; ++mt)
                #pragma unroll
                for (int r = 0; r < 4; ++r) {
                    const int row = mt * 16 + g * 4 + r;
                    if (row < 49) {
                        const size_t gi = base + (size_t)((row / 7) * 112 + (row % 7)) * 128 + oc;
                        out[gi] = x[gi] + acc[mt][ntl][r] + bias;
                    }
                }
        }
    } else {
        // ============ fallback: MO projection -> SX, barrier, OUT + residual ============
        {
            bf16x8 a[4][4];
            #pragma unroll
            for (int mt = 0; mt < 4; ++mt)
                #pragma unroll
                for (int kk = 0; kk < 4; ++kk) {
                    int row = mt * 16 + lr;
                    a[mt][kk] = *(bf16x8*)(lds + SAO + row * 256 + SWZ(g * 16 + kk * 64, row));
                }
            #pragma unroll
            for (int ntl = 0; ntl < 2; ++ntl) {
                const int oc = hb + ntl * 16 + lr;
                bf16x8 bfr[4];
                #pragma unroll
                for (int kk = 0; kk < 4; ++kk)
                    bfr[kk] = load_wfrag<false>(nullptr, wmo, oc * 128 + kk * 32 + g * 8);
                f32x4 acc[4];
                #pragma unroll
                for (int mt = 0; mt < 4; ++mt) acc[mt] = f32x4{0.f, 0.f, 0.f, 0.f};
                #pragma unroll
                for (int kk = 0; kk < 4; ++kk)
                    #pragma unroll
                    for (int mt = 0; mt < 4; ++mt)
                        acc[mt] = __builtin_amdgcn_mfma_f32_16x16x32_bf16(a[mt][kk], bfr[kk], acc[mt], 0, 0, 0);
                const float bias = bmo[oc];
                #pragma unroll
                for (int mt = 0; mt < 4; ++mt)
                    #pragma unroll
                    for (int r = 0; r < 4; ++r) {
                        int row = mt * 16 + g * 4 + r;
                        *(unsigned short*)(lds + SX + row * 256 + SWZ(oc * 2, row)) = b1(acc[mt][r] + bias);
                    }
            }
        }
        __syncthreads();
        {
            bf16x8 a[4][4];
            #pragma unroll
            for (int mt = 0; mt < 4; ++mt)
                #pragma unroll
                for (int kk = 0; kk < 4; ++kk) {
                    int row = mt * 16 + lr;
                    a[mt][kk] = *(bf16x8*)(lds + SX + row * 256 + SWZ(g * 16 + kk * 64, row));
                }
            #pragma unroll
            for (int ntl = 0; ntl < 2; ++ntl) {
                const int oc = hb + ntl * 16 + lr;
                bf16x8 bfr[4];
                #pragma unroll
                for (int kk = 0; kk < 4; ++kk)
                    bfr[kk] = load_wfrag<false>(nullptr, wout, oc * 128 + kk * 32 + g * 8);
                f32x4 acc[4];
                #pragma unroll
                for (int mt = 0; mt < 4; ++mt) acc[mt] = f32x4{0.f, 0.f, 0.f, 0.f};
                #pragma unroll
                for (int kk = 0; kk < 4; ++kk)
                    #pragma unroll
                    for (int mt = 0; mt < 4; ++mt)
                        acc[mt] = __builtin_amdgcn_mfma_f32_16x16x32_bf16(a[mt][kk], bfr[kk], acc[mt], 0, 0, 0);
                const float bias = bout[oc];
                #pragma unroll
                for (int mt = 0; mt < 4; ++mt)
                    #pragma unroll
                    for (int r = 0; r < 4; ++r) {
                        const int row = mt * 16 + g * 4 + r;
                        if (row < 49) {
                            const size_t gi = base + (size_t)((row / 7) * 112 + (row % 7)) * 128 + oc;
                            out[gi] = x[gi] + acc[mt][r] + bias;
                        }
                    }
            }
        }
    }
}

} // namespace

extern "C" void kernel_launch(void* const* d_in, const int* in_sizes, int n_in,
                              void* d_out, int out_size, void* d_ws, size_t ws_size,
                              hipStream_t stream) {
    const float* x    = (const float*)d_in[0];
    const float* lng  = (const float*)d_in[1];
    const float* lnb  = (const float*)d_in[2];
    const float* wqkv = (const float*)d_in[3];
    const float* bqkv = (const float*)d_in[4];
    const float* wmo  = (const float*)d_in[5];
    const float* bmo  = (const float*)d_in[6];
    const float* wout = (const float*)d_in[7];
    const float* bout = (const float*)d_in[8];
    float* out = (float*)d_out;

    if (ws_size >= 133120) {
        unsigned short* wsb = (unsigned short*)d_ws;
        conv_w2<<<259, 256, 0, stream>>>(wqkv, bqkv, wmo, bmo, wout, bout, lng, lnb, wsb);
        swin_mfma<true><<<4096, 256, 0, stream>>>(x, lng, lnb, wqkv, bqkv, wmo, bmo,
                                                  wout, bout, wsb, out);
    } else {
        swin_mfma<false><<<4096, 256, 0, stream>>>(x, lng, lnb, wqkv, bqkv, wmo, bmo,
                                                   wout, bout, nullptr, out);
    }
}

// Round 12
// 101.812 us; speedup vs baseline: 1.6796x; 1.0106x over previous
//
#include <hip/hip_runtime.h>
#include <hip/hip_bf16.h>

namespace {

typedef __attribute__((ext_vector_type(8))) short bf16x8;
typedef __attribute__((ext_vector_type(4))) float f32x4;

union BF8U { unsigned u[4]; bf16x8 v; };

__device__ __forceinline__ unsigned pk2(float a, float b) {
    union { __hip_bfloat162 h2; unsigned u; } c;
    c.h2 = __float22bfloat162_rn(float2{a, b});
    return c.u;
}
__device__ __forceinline__ unsigned short b1(float f) {
    union { __hip_bfloat16 h; unsigned short s; } c;
    c.h = __float2bfloat16(f);
    return c.s;
}
__device__ __forceinline__ int SWZ(int byteoff, int row) {
    return byteoff ^ ((row & 7) << 4);
}

// LDS: two 16 KB tiles, rows = 64 x 256B (128 bf16), XOR-swizzled.
constexpr int SX  = 0;        // LN out; (fallback path reuses as MO-out)
constexpr int SAO = 16384;    // attention out [i][d]
constexpr int LDS_BYTES = 32768;

// Workspace layout (USEWS):
//   shorts [0, 49152)      : bf16 Wqkv' = wqkv * diag(ln_gamma)   [384][128]
//   shorts [49152, 65536)  : bf16 Wcomb = wout @ wmo              [128][128]
//   floats fb[0, 384)      : bqkv' = bqkv + wqkv @ ln_beta
//   floats fb[384, 512)    : bcomb = bout + wout @ bmo
// fb = (float*)(wsb + 65536); total bytes = 131072 + 2048 = 133120.

template<bool USEWS>
__device__ __forceinline__ bf16x8 load_wfrag(const unsigned short* wsb, const float* wf, int idx) {
    if constexpr (USEWS) {
        return *(const bf16x8*)(wsb + idx);
    } else {
        const float4 f0 = *(const float4*)(wf + idx);
        const float4 f1 = *(const float4*)(wf + idx + 4);
        bf16x8 r;
        r[0] = (short)b1(f0.x); r[1] = (short)b1(f0.y);
        r[2] = (short)b1(f0.z); r[3] = (short)b1(f0.w);
        r[4] = (short)b1(f1.x); r[5] = (short)b1(f1.y);
        r[6] = (short)b1(f1.z); r[7] = (short)b1(f1.w);
        return r;
    }
}

__global__ void conv_w2(const float* __restrict__ wqkv, const float* __restrict__ bqkv,
                        const float* __restrict__ wmo,  const float* __restrict__ bmo,
                        const float* __restrict__ wout, const float* __restrict__ bout,
                        const float* __restrict__ lng,  const float* __restrict__ lnb,
                        unsigned short* __restrict__ dst) {
    float* fb = (float*)(dst + 65536);
    const int bid = blockIdx.x, t = threadIdx.x;
    if (bid < 192) {
        const int idx = bid * 256 + t;
        dst[idx] = b1(wqkv[idx] * lng[idx & 127]);
    } else if (bid < 256) {
        const int e = (bid - 192) * 256 + t;
        const int o = e >> 7, i = e & 127;
        const float* wo = wout + o * 128;
        float s = 0.f;
        for (int k = 0; k < 128; ++k) s += wo[k] * wmo[k * 128 + i];
        dst[49152 + e] = b1(s);
    } else if (bid < 258) {
        const int o = (bid - 256) * 256 + t;
        if (o < 384) {
            const float* wr = wqkv + o * 128;
            float s = 0.f;
            for (int i = 0; i < 128; ++i) s += wr[i] * lnb[i];
            fb[o] = bqkv[o] + s;
        }
    } else {
        if (t < 128) {
            const float* wo = wout + t * 128;
            float s = 0.f;
            for (int k = 0; k < 128; ++k) s += wo[k] * bmo[k];
            fb[384 + t] = bout[t] + s;
        }
    }
}

template<bool USEWS>
__global__ __launch_bounds__(256, 4)
void swin_mfma(const float* __restrict__ x,
               const float* __restrict__ lng, const float* __restrict__ lnb,
               const float* __restrict__ wqkv, const float* __restrict__ bqkv,
               const float* __restrict__ wmo,  const float* __restrict__ bmo,
               const float* __restrict__ wout, const float* __restrict__ bout,
               const unsigned short* __restrict__ wsb,
               float* __restrict__ out)
{
    __shared__ char lds[LDS_BYTES];

    const float* fb = USEWS ? (const float*)(wsb + 65536) : nullptr;

    const int wid  = blockIdx.x;
    const int b    = wid >> 8;
    const int wh   = (wid >> 4) & 15;
    const int ww   = wid & 15;
    const int t    = threadIdx.x;
    const int lane = t & 63;
    const int h    = t >> 6;          // wave == head
    const int lr   = lane & 15;
    const int g    = lane >> 4;       // 0..3
    const int hb   = h * 32;

    const size_t base = ((size_t)(b * 112 + wh * 7) * 112 + ww * 7) * 128;

    // ================= LayerNorm (4 lanes per token) =================
    if (t < 240) *(f32x4*)(lds + SX + 49 * 256 + t * 16) = f32x4{0.f, 0.f, 0.f, 0.f};
    {
        const int tok = t >> 2, q4 = t & 3;
        if (tok < 49) {
            const float* xr = x + base + (size_t)((tok / 7) * 112 + (tok % 7)) * 128;
            float4 xv[8];
            float s1 = 0.f, s2 = 0.f;
            #pragma unroll
            for (int j = 0; j < 8; ++j) {
                xv[j] = *(const float4*)(xr + j * 16 + q4 * 4);
                s1 += xv[j].x + xv[j].y + xv[j].z + xv[j].w;
                s2 += xv[j].x * xv[j].x + xv[j].y * xv[j].y
                    + xv[j].z * xv[j].z + xv[j].w * xv[j].w;
            }
            s1 += __shfl_xor(s1, 1); s1 += __shfl_xor(s1, 2);
            s2 += __shfl_xor(s2, 1); s2 += __shfl_xor(s2, 2);
            const float mu  = s1 * (1.f / 128.f);
            const float inv = rsqrtf(s2 * (1.f / 128.f) - mu * mu + 1e-5f);
            #pragma unroll
            for (int j = 0; j < 8; ++j) {
                float y0, y1, y2, y3;
                if constexpr (USEWS) {
                    y0 = (xv[j].x - mu) * inv;
                    y1 = (xv[j].y - mu) * inv;
                    y2 = (xv[j].z - mu) * inv;
                    y3 = (xv[j].w - mu) * inv;
                } else {
                    const float4 gm = *(const float4*)(lng + j * 16 + q4 * 4);
                    const float4 bt = *(const float4*)(lnb + j * 16 + q4 * 4);
                    y0 = (xv[j].x - mu) * inv * gm.x + bt.x;
                    y1 = (xv[j].y - mu) * inv * gm.y + bt.y;
                    y2 = (xv[j].z - mu) * inv * gm.z + bt.z;
                    y3 = (xv[j].w - mu) * inv * gm.w + bt.w;
                }
                uint2 w; w.x = pk2(y0, y1); w.y = pk2(y2, y3);
                *(uint2*)(lds + SX + tok * 256 + SWZ(j * 32 + q4 * 8, tok)) = w;
            }
        }
    }
    __syncthreads();   // barrier #1

    // ---- in-wave redistribution: C-frag (idx on g*4+r, tiles) -> A/B-frag (idx on g*8+d) ----
    const int s01  = lr + ((lane & 16) ? 32 : 0);   // src lane for words 0,1
    const int s23  = s01 + 16;                      // src lane for words 2,3
    const bool hiT = (lane & 32) != 0;              // tile-parity select
    auto RD4 = [&](unsigned e0, unsigned e1, unsigned o0, unsigned o1) -> bf16x8 {
        BF8U r;
        const unsigned v0 = hiT ? o0 : e0;
        const unsigned v1 = hiT ? o1 : e1;
        r.u[0] = (unsigned)__shfl((int)v0, s01);
        r.u[1] = (unsigned)__shfl((int)v1, s01);
        r.u[2] = (unsigned)__shfl((int)v0, s23);
        r.u[3] = (unsigned)__shfl((int)v1, s23);
        return r.v;
    };

    // ============ Q pass: projection SWAPPED (D[o][token]) ============
    unsigned pkQ[4][2][2];   // [token-tile][o-tile][pair]
    {
        f32x4 aQ[2][4];
        #pragma unroll
        for (int ot = 0; ot < 2; ++ot)
            #pragma unroll
            for (int tt = 0; tt < 4; ++tt) aQ[ot][tt] = f32x4{0.f, 0.f, 0.f, 0.f};
        #pragma unroll
        for (int kk = 0; kk < 4; ++kk) {
            bf16x8 xa[4];
            #pragma unroll
            for (int tt = 0; tt < 4; ++tt) {
                int row = tt * 16 + lr;
                xa[tt] = *(bf16x8*)(lds + SX + row * 256 + SWZ(kk * 64 + g * 16, row));
            }
            #pragma unroll
            for (int ot = 0; ot < 2; ++ot) {
                bf16x8 wq = load_wfrag<USEWS>(wsb, wqkv, (hb + ot * 16 + lr) * 128 + kk * 32 + g * 8);
                __builtin_amdgcn_s_setprio(1);
                #pragma unroll
                for (int tt = 0; tt < 4; ++tt)
                    aQ[ot][tt] = __builtin_amdgcn_mfma_f32_16x16x32_bf16(wq, xa[tt], aQ[ot][tt], 0, 0, 0);
                __builtin_amdgcn_s_setprio(0);
            }
        }
        #pragma unroll
        for (int ot = 0; ot < 2; ++ot) {
            float4 bq;
            if constexpr (USEWS) bq = *(const float4*)(fb + hb + ot * 16 + g * 4);
            else                 bq = *(const float4*)(bqkv + hb + ot * 16 + g * 4);
            #pragma unroll
            for (int nti = 0; nti < 4; ++nti) {
                const float q0 = (aQ[ot][nti][0] + bq.x) * 0.17677669529663687f;
                const float q1 = (aQ[ot][nti][1] + bq.y) * 0.17677669529663687f;
                const float q2 = (aQ[ot][nti][2] + bq.z) * 0.17677669529663687f;
                const float q3 = (aQ[ot][nti][3] + bq.w) * 0.17677669529663687f;
                pkQ[nti][ot][0] = pk2(q0, q1); pkQ[nti][ot][1] = pk2(q2, q3);
            }
        }
    }
    asm volatile("" ::: "memory");

    // ============ K pass: projection SWAPPED (D[o][token]) ============
    unsigned pkK[4][2][2];
    {
        f32x4 aK[2][4];
        #pragma unroll
        for (int ot = 0; ot < 2; ++ot)
            #pragma unroll
            for (int tt = 0; tt < 4; ++tt) aK[ot][tt] = f32x4{0.f, 0.f, 0.f, 0.f};
        #pragma unroll
        for (int kk = 0; kk < 4; ++kk) {
            bf16x8 xa[4];
            #pragma unroll
            for (int tt = 0; tt < 4; ++tt) {
                int row = tt * 16 + lr;
                xa[tt] = *(bf16x8*)(lds + SX + row * 256 + SWZ(kk * 64 + g * 16, row));
            }
            #pragma unroll
            for (int ot = 0; ot < 2; ++ot) {
                bf16x8 wk = load_wfrag<USEWS>(wsb, wqkv, (128 + hb + ot * 16 + lr) * 128 + kk * 32 + g * 8);
                __builtin_amdgcn_s_setprio(1);
                #pragma unroll
                for (int tt = 0; tt < 4; ++tt)
                    aK[ot][tt] = __builtin_amdgcn_mfma_f32_16x16x32_bf16(wk, xa[tt], aK[ot][tt], 0, 0, 0);
                __builtin_amdgcn_s_setprio(0);
            }
        }
        #pragma unroll
        for (int ot = 0; ot < 2; ++ot) {
            float4 bk;
            if constexpr (USEWS) bk = *(const float4*)(fb + 128 + hb + ot * 16 + g * 4);
            else                 bk = *(const float4*)(bqkv + 128 + hb + ot * 16 + g * 4);
            #pragma unroll
            for (int nti = 0; nti < 4; ++nti) {
                pkK[nti][ot][0] = pk2(aK[ot][nti][0] + bk.x, aK[ot][nti][1] + bk.y);
                pkK[nti][ot][1] = pk2(aK[ot][nti][2] + bk.z, aK[ot][nti][3] + bk.w);
            }
        }
    }
    asm volatile("" ::: "memory");

    // ============ scores S[j][i] = mfma(K, Q) + softmax, i-tiles in 2 halves ============
    unsigned pkP[4][4][2];   // [i-tile][j-tile][pair]
    #pragma unroll
    for (int half = 0; half < 2; ++half) {
        f32x4 S[4][2];   // [j-tile][i-within-half]
        bf16x8 qb[2];
        #pragma unroll
        for (int ni = 0; ni < 2; ++ni) {
            const int nti = half * 2 + ni;
            qb[ni] = RD4(pkQ[nti][0][0], pkQ[nti][0][1], pkQ[nti][1][0], pkQ[nti][1][1]);
        }
        #pragma unroll
        for (int mtj = 0; mtj < 4; ++mtj) {
            bf16x8 ka = RD4(pkK[mtj][0][0], pkK[mtj][0][1], pkK[mtj][1][0], pkK[mtj][1][1]);
            __builtin_amdgcn_s_setprio(1);
            #pragma unroll
            for (int ni = 0; ni < 2; ++ni)
                S[mtj][ni] = __builtin_amdgcn_mfma_f32_16x16x32_bf16(ka, qb[ni],
                                                                     f32x4{0.f, 0.f, 0.f, 0.f}, 0, 0, 0);
            __builtin_amdgcn_s_setprio(0);
        }
        // mask keys j >= 49 (j = 48 + g*4 + r in tile 3)
        #pragma unroll
        for (int ni = 0; ni < 2; ++ni)
            #pragma unroll
            for (int r = 0; r < 4; ++r)
                if (r != 0 || g != 0) S[3][ni][r] = -1e30f;

        #pragma unroll
        for (int ni = 0; ni < 2; ++ni) {
            const int nti = half * 2 + ni;
            float m = S[0][ni][0];
            #pragma unroll
            for (int mtj = 0; mtj < 4; ++mtj)
                #pragma unroll
                for (int r = 0; r < 4; ++r) m = fmaxf(m, S[mtj][ni][r]);
            m = fmaxf(m, __shfl_xor(m, 16));
            m = fmaxf(m, __shfl_xor(m, 32));
            float sum = 0.f;
            #pragma unroll
            for (int mtj = 0; mtj < 4; ++mtj)
                #pragma unroll
                for (int r = 0; r < 4; ++r) {
                    const float p = __expf(S[mtj][ni][r] - m);
                    S[mtj][ni][r] = p;
                    sum += p;
                }
            sum += __shfl_xor(sum, 16);
            sum += __shfl_xor(sum, 32);
            const float rinv = 1.0f / sum;
            #pragma unroll
            for (int mtj = 0; mtj < 4; ++mtj) {
                pkP[nti][mtj][0] = pk2(S[mtj][ni][0] * rinv, S[mtj][ni][1] * rinv);
                pkP[nti][mtj][1] = pk2(S[mtj][ni][2] * rinv, S[mtj][ni][3] * rinv);
            }
        }
    }
    // NOTE: no scheduling fence here — let V-pass weight loads issue under softmax.

    // ============ V pass: projection NORMAL (D[token][o]) ============
    unsigned pkV[2][4][2];   // [d-tile][token-tile][pair]
    {
        f32x4 aV[4][2];
        #pragma unroll
        for (int mt = 0; mt < 4; ++mt) {
            aV[mt][0] = f32x4{0.f, 0.f, 0.f, 0.f};
            aV[mt][1] = f32x4{0.f, 0.f, 0.f, 0.f};
        }
        #pragma unroll
        for (int kk = 0; kk < 4; ++kk) {
            bf16x8 xa[4];
            #pragma unroll
            for (int tt = 0; tt < 4; ++tt) {
                int row = tt * 16 + lr;
                xa[tt] = *(bf16x8*)(lds + SX + row * 256 + SWZ(kk * 64 + g * 16, row));
            }
            bf16x8 wv0 = load_wfrag<USEWS>(wsb, wqkv, (256 + hb + lr) * 128 + kk * 32 + g * 8);
            bf16x8 wv1 = load_wfrag<USEWS>(wsb, wqkv, (256 + hb + 16 + lr) * 128 + kk * 32 + g * 8);
            __builtin_amdgcn_s_setprio(1);
            #pragma unroll
            for (int mt = 0; mt < 4; ++mt) {
                aV[mt][0] = __builtin_amdgcn_mfma_f32_16x16x32_bf16(xa[mt], wv0, aV[mt][0], 0, 0, 0);
                aV[mt][1] = __builtin_amdgcn_mfma_f32_16x16x32_bf16(xa[mt], wv1, aV[mt][1], 0, 0, 0);
            }
            __builtin_amdgcn_s_setprio(0);
        }
        const float bv0 = USEWS ? fb[256 + hb + lr]      : bqkv[256 + hb + lr];
        const float bv1 = USEWS ? fb[256 + hb + 16 + lr] : bqkv[256 + hb + 16 + lr];
        #pragma unroll
        for (int mt = 0; mt < 4; ++mt) {
            pkV[0][mt][0] = pk2(aV[mt][0][0] + bv0, aV[mt][0][1] + bv0);
            pkV[0][mt][1] = pk2(aV[mt][0][2] + bv0, aV[mt][0][3] + bv0);
            pkV[1][mt][0] = pk2(aV[mt][1][0] + bv1, aV[mt][1][1] + bv1);
            pkV[1][mt][1] = pk2(aV[mt][1][2] + bv1, aV[mt][1][3] + bv1);
        }
    }
    asm volatile("" ::: "memory");

    // ---- prefetch fused-GEMM weights (Wcomb) + bias so post-barrier phase has no load waits.
    //      32 VGPRs; current allocation 56 -> ~90, under the 128-reg cap at 4 waves/SIMD. ----
    bf16x8 wc0[4], wc1[4];
    float pbias0 = 0.f, pbias1 = 0.f;
    if constexpr (USEWS) {
        #pragma unroll
        for (int kk = 0; kk < 4; ++kk) {
            wc0[kk] = *(const bf16x8*)(wsb + 49152 + (hb + lr) * 128 + kk * 32 + g * 8);
            wc1[kk] = *(const bf16x8*)(wsb + 49152 + (hb + 16 + lr) * 128 + kk * 32 + g * 8);
        }
        pbias0 = fb[384 + hb + lr];
        pbias1 = fb[384 + hb + 16 + lr];
    }

    // ============ PV: O = P @ V ============
    {
        bf16x8 vb[2][2];   // [kk][d-tile]
        #pragma unroll
        for (int kk = 0; kk < 2; ++kk)
            #pragma unroll
            for (int ntd = 0; ntd < 2; ++ntd)
                vb[kk][ntd] = RD4(pkV[ntd][2 * kk][0], pkV[ntd][2 * kk][1],
                                  pkV[ntd][2 * kk + 1][0], pkV[ntd][2 * kk + 1][1]);
        #pragma unroll
        for (int mti = 0; mti < 4; ++mti) {
            bf16x8 pa0 = RD4(pkP[mti][0][0], pkP[mti][0][1], pkP[mti][1][0], pkP[mti][1][1]);
            bf16x8 pa1 = RD4(pkP[mti][2][0], pkP[mti][2][1], pkP[mti][3][0], pkP[mti][3][1]);
            f32x4 O0 = f32x4{0.f, 0.f, 0.f, 0.f}, O1 = O0;
            __builtin_amdgcn_s_setprio(1);
            O0 = __builtin_amdgcn_mfma_f32_16x16x32_bf16(pa0, vb[0][0], O0, 0, 0, 0);
            O0 = __builtin_amdgcn_mfma_f32_16x16x32_bf16(pa1, vb[1][0], O0, 0, 0, 0);
            O1 = __builtin_amdgcn_mfma_f32_16x16x32_bf16(pa0, vb[0][1], O1, 0, 0, 0);
            O1 = __builtin_amdgcn_mfma_f32_16x16x32_bf16(pa1, vb[1][1], O1, 0, 0, 0);
            __builtin_amdgcn_s_setprio(0);
            #pragma unroll
            for (int r = 0; r < 4; ++r) {
                const int i = mti * 16 + g * 4 + r;
                *(unsigned short*)(lds + SAO + i * 256 + SWZ((hb + lr) * 2, i))      = b1(O0[r]);
                *(unsigned short*)(lds + SAO + i * 256 + SWZ((hb + 16 + lr) * 2, i)) = b1(O1[r]);
            }
        }
    }
    __syncthreads();   // barrier #2

    if constexpr (USEWS) {
        // ============ fused (MO∘OUT) projection + residual, kk-outer, weights prefetched ============
        f32x4 acc[4][2];
        #pragma unroll
        for (int mt = 0; mt < 4; ++mt) {
            acc[mt][0] = f32x4{0.f, 0.f, 0.f, 0.f};
            acc[mt][1] = f32x4{0.f, 0.f, 0.f, 0.f};
        }
        #pragma unroll
        for (int kk = 0; kk < 4; ++kk) {
            bf16x8 a4[4];
            #pragma unroll
            for (int mt = 0; mt < 4; ++mt) {
                int row = mt * 16 + lr;
                a4[mt] = *(bf16x8*)(lds + SAO + row * 256 + SWZ(g * 16 + kk * 64, row));
            }
            __builtin_amdgcn_s_setprio(1);
            #pragma unroll
            for (int mt = 0; mt < 4; ++mt) {
                acc[mt][0] = __builtin_amdgcn_mfma_f32_16x16x32_bf16(a4[mt], wc0[kk], acc[mt][0], 0, 0, 0);
                acc[mt][1] = __builtin_amdgcn_mfma_f32_16x16x32_bf16(a4[mt], wc1[kk], acc[mt][1], 0, 0, 0);
            }
            __builtin_amdgcn_s_setprio(0);
        }
        #pragma unroll
        for (int ntl = 0; ntl < 2; ++ntl) {
            const int oc = hb + ntl * 16 + lr;
            const float bias = ntl == 0 ? pbias0 : pbias1;
            #pragma unroll
            for (int mt = 0; mt < 4; ++mt)
                #pragma unroll
                for (int r = 0; r < 4; ++r) {
                    const int row = mt * 16 + g * 4 + r;
                    if (row < 49) {
                        const size_t gi = base + (size_t)((row / 7) * 112 + (row % 7)) * 128 + oc;
                        out[gi] = x[gi] + acc[mt][ntl][r] + bias;
                    }
                }
        }
    } else {
        // ============ fallback: MO projection -> SX, barrier, OUT + residual ============
        {
            bf16x8 a[4][4];
            #pragma unroll
            for (int mt = 0; mt < 4; ++mt)
                #pragma unroll
                for (int kk = 0; kk < 4; ++kk) {
                    int row = mt * 16 + lr;
                    a[mt][kk] = *(bf16x8*)(lds + SAO + row * 256 + SWZ(g * 16 + kk * 64, row));
                }
            #pragma unroll
            for (int ntl = 0; ntl < 2; ++ntl) {
                const int oc = hb + ntl * 16 + lr;
                bf16x8 bfr[4];
                #pragma unroll
                for (int kk = 0; kk < 4; ++kk)
                    bfr[kk] = load_wfrag<false>(nullptr, wmo, oc * 128 + kk * 32 + g * 8);
                f32x4 acc[4];
                #pragma unroll
                for (int mt = 0; mt < 4; ++mt) acc[mt] = f32x4{0.f, 0.f, 0.f, 0.f};
                #pragma unroll
                for (int kk = 0; kk < 4; ++kk)
                    #pragma unroll
                    for (int mt = 0; mt < 4; ++mt)
                        acc[mt] = __builtin_amdgcn_mfma_f32_16x16x32_bf16(a[mt][kk], bfr[kk], acc[mt], 0, 0, 0);
                const float bias = bmo[oc];
                #pragma unroll
                for (int mt = 0; mt < 4; ++mt)
                    #pragma unroll
                    for (int r = 0; r < 4; ++r) {
                        int row = mt * 16 + g * 4 + r;
                        *(unsigned short*)(lds + SX + row * 256 + SWZ(oc * 2, row)) = b1(acc[mt][r] + bias);
                    }
            }
        }
        __syncthreads();
        {
            bf16x8 a[4][4];
            #pragma unroll
            for (int mt = 0; mt < 4; ++mt)
                #pragma unroll
                for (int kk = 0; kk < 4; ++kk) {
                    int row = mt * 16 + lr;
                    a[mt][kk] = *(bf16x8*)(lds + SX + row * 256 + SWZ(g * 16 + kk * 64, row));
                }
            #pragma unroll
            for (int ntl = 0; ntl < 2; ++ntl) {
                const int oc = hb + ntl * 16 + lr;
                bf16x8 bfr[4];
                #pragma unroll
                for (int kk = 0; kk < 4; ++kk)
                    bfr[kk] = load_wfrag<false>(nullptr, wout, oc * 128 + kk * 32 + g * 8);
                f32x4 acc[4];
                #pragma unroll
                for (int mt = 0; mt < 4; ++mt) acc[mt] = f32x4{0.f, 0.f, 0.f, 0.f};
                #pragma unroll
                for (int kk = 0; kk < 4; ++kk)
                    #pragma unroll
                    for (int mt = 0; mt < 4; ++mt)
                        acc[mt] = __builtin_amdgcn_mfma_f32_16x16x32_bf16(a[mt][kk], bfr[kk], acc[mt], 0, 0, 0);
                const float bias = bout[oc];
                #pragma unroll
                for (int mt = 0; mt < 4; ++mt)
                    #pragma unroll
                    for (int r = 0; r < 4; ++r) {
                        const int row = mt * 16 + g * 4 + r;
                        if (row < 49) {
                            const size_t gi = base + (size_t)((row / 7) * 112 + (row % 7)) * 128 + oc;
                            out[gi] = x[gi] + acc[mt][r] + bias;
                        }
                    }
            }
        }
    }
}

} // namespace

extern "C" void kernel_launch(void* const* d_in, const int* in_sizes, int n_in,
                              void* d_out, int out_size, void* d_ws, size_t ws_size,
                              hipStream_t stream) {
    const float* x    = (const float*)d_in[0];
    const float* lng  = (const float*)d_in[1];
    const float* lnb  = (const float*)d_in[2];
    const float* wqkv = (const float*)d_in[3];
    const float* bqkv = (const float*)d_in[4];
    const float* wmo  = (const float*)d_in[5];
    const float* bmo  = (const float*)d_in[6];
    const float* wout = (const float*)d_in[7];
    const float* bout = (const float*)d_in[8];
    float* out = (float*)d_out;

    if (ws_size >= 133120) {
        unsigned short* wsb = (unsigned short*)d_ws;
        conv_w2<<<259, 256, 0, stream>>>(wqkv, bqkv, wmo, bmo, wout, bout, lng, lnb, wsb);
        swin_mfma<true><<<4096, 256, 0, stream>>>(x, lng, lnb, wqkv, bqkv, wmo, bmo,
                                                  wout, bout, wsb, out);
    } else {
        swin_mfma<false><<<4096, 256, 0, stream>>>(x, lng, lnb, wqkv, bqkv, wmo, bmo,
                                                   wout, bout, nullptr, out);
    }
}